// Round 1
// baseline (2577.025 us; speedup 1.0000x reference)
//
#include <hip/hip_runtime.h>
#include <cstddef>

#define DIM   256
#define NEMB  8192
#define NROWS 32768
#define TM    16
#define TK    4

// ---------- helpers ----------
__device__ __forceinline__ bool better(float va, int ia, float vb, int ib) {
  return (va < vb) || (va == vb && ia < ib);
}

__device__ __forceinline__ void top2_update(float& v1, int& i1, float& v2, int& i2,
                                            float d, int k) {
  if (better(d, k, v1, i1)) { v2 = v1; i2 = i1; v1 = d; i1 = k; }
  else if (better(d, k, v2, i2)) { v2 = d; i2 = k; }
}

// merge top2 {b1,b2} (b1 better than b2) into {a1,a2}
__device__ __forceinline__ void merge_top2(float& a1, int& ia1, float& a2, int& ia2,
                                           float b1, int ib1, float b2, int ib2) {
  if (better(b1, ib1, a1, ia1)) {
    if (better(b2, ib2, a1, ia1)) { a1 = b1; ia1 = ib1; a2 = b2; ia2 = ib2; }
    else                          { a2 = a1; ia2 = ia1; a1 = b1; ia1 = ib1; }
  } else {
    if (better(b1, ib1, a2, ia2)) { a2 = b1; ia2 = ib1; }
  }
}

__device__ __forceinline__ void fma4(float4& a, float s, const float4& b) {
  a.x += s * b.x; a.y += s * b.y; a.z += s * b.z; a.w += s * b.w;
}

// ---------- transpose: embedT[k*DIM + d] = embed[d*NEMB + k] ----------
__global__ __launch_bounds__(256) void transpose_kernel(const float* __restrict__ embed,
                                                        float* __restrict__ embedT) {
  __shared__ float tile[64][65];  // +1 pad: conflict-free
  const int tx = threadIdx.x & 63;
  const int ty = threadIdx.x >> 6;  // 0..3
  const int k0 = blockIdx.x * 64;
  const int d0 = blockIdx.y * 64;
  #pragma unroll
  for (int i = 0; i < 16; ++i) {
    const int dl = ty + i * 4;
    tile[dl][tx] = embed[(size_t)(d0 + dl) * NEMB + k0 + tx];
  }
  __syncthreads();
  #pragma unroll
  for (int i = 0; i < 16; ++i) {
    const int kl = ty + i * 4;
    embedT[(size_t)(k0 + kl) * DIM + d0 + tx] = tile[tx][kl];
  }
}

// ---------- e_sq[k] = sum_d embed[d][k]^2 ----------
__global__ __launch_bounds__(256) void esq_kernel(const float* __restrict__ embed,
                                                  float* __restrict__ e_sq) {
  const int k = blockIdx.x * 256 + threadIdx.x;
  float s = 0.f;
  #pragma unroll 4
  for (int d = 0; d < DIM; ++d) {
    const float v = embed[(size_t)d * NEMB + k];
    s += v * v;
  }
  e_sq[k] = s;
}

// ---------- main: fused distance + per-row top-2 argmin ----------
__global__ __launch_bounds__(256) void argmin_kernel(
    const float* __restrict__ x, const float* __restrict__ embed,
    const float* __restrict__ e_sq, int* __restrict__ out_i1, int* __restrict__ out_i2) {
  __shared__ float xs[TM][DIM];               // 16 KB
  __shared__ float rv1[4][TM], rv2[4][TM];
  __shared__ int   rj1[4][TM], rj2[4][TM];

  const int tid  = threadIdx.x;
  const int row0 = blockIdx.x * TM;

  {  // stage TM rows of x (coalesced float4)
    const float4* src = (const float4*)(x + (size_t)row0 * DIM);
    float4* dst = (float4*)xs;
    #pragma unroll
    for (int i = 0; i < (TM * DIM / 4) / 256; ++i)
      dst[tid + 256 * i] = src[tid + 256 * i];
  }
  __syncthreads();

  float v1[TM], v2[TM];
  int   j1[TM], j2[TM];
  #pragma unroll
  for (int r = 0; r < TM; ++r) {
    v1[r] = __builtin_inff(); v2[r] = __builtin_inff();
    j1[r] = 0x7fffffff;       j2[r] = 0x7fffffff;
  }

  for (int c = 0; c < NEMB / (256 * TK); ++c) {   // 8 k-chunks of 1024
    const int k = c * (256 * TK) + tid * TK;      // this thread's 4 consecutive k
    float4 acc[TM];
    #pragma unroll
    for (int r = 0; r < TM; ++r) acc[r] = make_float4(0.f, 0.f, 0.f, 0.f);

    const float* eb = embed + k;
    #pragma unroll 2
    for (int d4 = 0; d4 < DIM / 4; ++d4) {
      const int d = d4 * 4;
      const float4 e0 = *(const float4*)(eb + (size_t)(d + 0) * NEMB);
      const float4 e1 = *(const float4*)(eb + (size_t)(d + 1) * NEMB);
      const float4 e2 = *(const float4*)(eb + (size_t)(d + 2) * NEMB);
      const float4 e3 = *(const float4*)(eb + (size_t)(d + 3) * NEMB);
      #pragma unroll
      for (int r = 0; r < TM; ++r) {
        const float4 xv = *(const float4*)&xs[r][d];  // broadcast ds_read_b128
        fma4(acc[r], xv.x, e0);
        fma4(acc[r], xv.y, e1);
        fma4(acc[r], xv.z, e2);
        fma4(acc[r], xv.w, e3);
      }
    }

    const float4 es = *(const float4*)(e_sq + k);
    #pragma unroll
    for (int r = 0; r < TM; ++r) {
      top2_update(v1[r], j1[r], v2[r], j2[r], es.x - 2.f * acc[r].x, k + 0);
      top2_update(v1[r], j1[r], v2[r], j2[r], es.y - 2.f * acc[r].y, k + 1);
      top2_update(v1[r], j1[r], v2[r], j2[r], es.z - 2.f * acc[r].z, k + 2);
      top2_update(v1[r], j1[r], v2[r], j2[r], es.w - 2.f * acc[r].w, k + 3);
    }
  }

  // wave-level butterfly merge (k-sets are disjoint across threads)
  const int lane = tid & 63;
  const int wv   = tid >> 6;
  #pragma unroll
  for (int r = 0; r < TM; ++r) {
    float a1 = v1[r], a2 = v2[r];
    int ia1 = j1[r], ia2 = j2[r];
    #pragma unroll
    for (int m = 1; m < 64; m <<= 1) {
      const float b1 = __shfl_xor(a1, m);
      const int  ib1 = __shfl_xor(ia1, m);
      const float b2 = __shfl_xor(a2, m);
      const int  ib2 = __shfl_xor(ia2, m);
      merge_top2(a1, ia1, a2, ia2, b1, ib1, b2, ib2);
    }
    if (lane == 0) { rv1[wv][r] = a1; rv2[wv][r] = a2; rj1[wv][r] = ia1; rj2[wv][r] = ia2; }
  }
  __syncthreads();

  if (tid < TM) {
    float a1 = rv1[0][tid], a2 = rv2[0][tid];
    int ia1 = rj1[0][tid], ia2 = rj2[0][tid];
    #pragma unroll
    for (int w = 1; w < 4; ++w)
      merge_top2(a1, ia1, a2, ia2, rv1[w][tid], rj1[w][tid], rv2[w][tid], rj2[w][tid]);
    out_i1[row0 + tid] = ia1;
    out_i2[row0 + tid] = ia2;
  }
}

// ---------- refine (fp64 decide between top-2) + gather ----------
template <bool USE_T>
__global__ __launch_bounds__(256) void refine_gather_kernel(
    const float* __restrict__ x, const float* __restrict__ embed,
    const float* __restrict__ embedT, const int* __restrict__ in_i1,
    const int* __restrict__ in_i2, float* __restrict__ out) {
  const int lane = threadIdx.x & 63;
  const int row  = blockIdx.x * (blockDim.x >> 6) + (threadIdx.x >> 6);  // one wave per row
  const int k1 = in_i1[row];
  const int k2 = in_i2[row];

  const float4 xv = *(const float4*)(x + (size_t)row * DIM + lane * 4);
  float4 e1v, e2v;
  if (USE_T) {
    e1v = *(const float4*)(embedT + (size_t)k1 * DIM + lane * 4);
    e2v = *(const float4*)(embedT + (size_t)k2 * DIM + lane * 4);
  } else {
    const int d = lane * 4;
    e1v.x = embed[(size_t)(d + 0) * NEMB + k1]; e1v.y = embed[(size_t)(d + 1) * NEMB + k1];
    e1v.z = embed[(size_t)(d + 2) * NEMB + k1]; e1v.w = embed[(size_t)(d + 3) * NEMB + k1];
    e2v.x = embed[(size_t)(d + 0) * NEMB + k2]; e2v.y = embed[(size_t)(d + 1) * NEMB + k2];
    e2v.z = embed[(size_t)(d + 2) * NEMB + k2]; e2v.w = embed[(size_t)(d + 3) * NEMB + k2];
  }

  double dot1 = (double)xv.x * e1v.x + (double)xv.y * e1v.y +
                (double)xv.z * e1v.z + (double)xv.w * e1v.w;
  double dot2 = (double)xv.x * e2v.x + (double)xv.y * e2v.y +
                (double)xv.z * e2v.z + (double)xv.w * e2v.w;
  double q1 = (double)e1v.x * e1v.x + (double)e1v.y * e1v.y +
              (double)e1v.z * e1v.z + (double)e1v.w * e1v.w;
  double q2 = (double)e2v.x * e2v.x + (double)e2v.y * e2v.y +
              (double)e2v.z * e2v.z + (double)e2v.w * e2v.w;

  #pragma unroll
  for (int m = 1; m < 64; m <<= 1) {
    dot1 += __shfl_xor(dot1, m);
    dot2 += __shfl_xor(dot2, m);
    q1   += __shfl_xor(q1, m);
    q2   += __shfl_xor(q2, m);
  }

  const double dist1 = q1 - 2.0 * dot1;
  const double dist2 = q2 - 2.0 * dot2;
  const bool pick1 = (dist1 < dist2) || (dist1 == dist2 && k1 <= k2);
  *(float4*)(out + (size_t)row * DIM + lane * 4) = pick1 ? e1v : e2v;
}

// ---------- launch ----------
extern "C" void kernel_launch(void* const* d_in, const int* in_sizes, int n_in,
                              void* d_out, int out_size, void* d_ws, size_t ws_size,
                              hipStream_t stream) {
  const float* x     = (const float*)d_in[0];
  const float* embed = (const float*)d_in[1];
  float* out = (float*)d_out;

  char* ws = (char*)d_ws;
  const size_t embT_bytes = (size_t)NEMB * DIM * sizeof(float);  // 8 MB
  const size_t esq_bytes  = (size_t)NEMB * sizeof(float);        // 32 KB
  const size_t idx_bytes  = (size_t)NROWS * sizeof(int);         // 128 KB
  const bool full = ws_size >= embT_bytes + esq_bytes + 2 * idx_bytes;

  float* embedT; float* e_sq; int* i1; int* i2;
  if (full) {
    embedT = (float*)ws;
    e_sq   = (float*)(ws + embT_bytes);
    i1     = (int*)(ws + embT_bytes + esq_bytes);
  } else {
    embedT = nullptr;
    e_sq   = (float*)ws;
    i1     = (int*)(ws + esq_bytes);
  }
  i2 = i1 + NROWS;

  if (full)
    transpose_kernel<<<dim3(NEMB / 64, DIM / 64), 256, 0, stream>>>(embed, embedT);
  esq_kernel<<<NEMB / 256, 256, 0, stream>>>(embed, e_sq);
  argmin_kernel<<<NROWS / TM, 256, 0, stream>>>(x, embed, e_sq, i1, i2);
  if (full)
    refine_gather_kernel<true><<<NROWS / 4, 256, 0, stream>>>(x, embed, embedT, i1, i2, out);
  else
    refine_gather_kernel<false><<<NROWS / 4, 256, 0, stream>>>(x, embed, nullptr, i1, i2, out);
}

// Round 2
// 1740.063 us; speedup vs baseline: 1.4810x; 1.4810x over previous
//
#include <hip/hip_runtime.h>
#include <cstddef>

#define DIM   256
#define NEMB  8192
#define NROWS 32768
#define TM    16
#define TK    4

typedef __attribute__((ext_vector_type(8))) short short8;
typedef __attribute__((ext_vector_type(4))) float f32x4;

// ---------- helpers ----------
__device__ __forceinline__ bool better(float va, int ia, float vb, int ib) {
  return (va < vb) || (va == vb && ia < ib);
}

__device__ __forceinline__ void top2_update(float& v1, int& i1, float& v2, int& i2,
                                            float d, int k) {
  if (better(d, k, v1, i1)) { v2 = v1; i2 = i1; v1 = d; i1 = k; }
  else if (better(d, k, v2, i2)) { v2 = d; i2 = k; }
}

__device__ __forceinline__ void merge_top2(float& a1, int& ia1, float& a2, int& ia2,
                                           float b1, int ib1, float b2, int ib2) {
  if (better(b1, ib1, a1, ia1)) {
    if (better(b2, ib2, a1, ia1)) { a1 = b1; ia1 = ib1; a2 = b2; ia2 = ib2; }
    else                          { a2 = a1; ia2 = ia1; a1 = b1; ia1 = ib1; }
  } else {
    if (better(b1, ib1, a2, ia2)) { a2 = b1; ia2 = ib1; }
  }
}

__device__ __forceinline__ void fma4(float4& a, float s, const float4& b) {
  a.x += s * b.x; a.y += s * b.y; a.z += s * b.z; a.w += s * b.w;
}

__device__ __forceinline__ unsigned short f2bf_rne(float f) {
  unsigned int u = __float_as_uint(f);
  u += 0x7FFFu + ((u >> 16) & 1u);
  return (unsigned short)(u >> 16);
}
__device__ __forceinline__ float bf2f(unsigned short h) {
  return __uint_as_float(((unsigned int)h) << 16);
}

// ---------- transpose: embedT[k*DIM + d] = embed[d*NEMB + k] ----------
__global__ __launch_bounds__(256) void transpose_kernel(const float* __restrict__ embed,
                                                        float* __restrict__ embedT) {
  __shared__ float tile[64][65];
  const int tx = threadIdx.x & 63;
  const int ty = threadIdx.x >> 6;
  const int k0 = blockIdx.x * 64;
  const int d0 = blockIdx.y * 64;
  #pragma unroll
  for (int i = 0; i < 16; ++i) {
    const int dl = ty + i * 4;
    tile[dl][tx] = embed[(size_t)(d0 + dl) * NEMB + k0 + tx];
  }
  __syncthreads();
  #pragma unroll
  for (int i = 0; i < 16; ++i) {
    const int kl = ty + i * 4;
    embedT[(size_t)(k0 + kl) * DIM + d0 + tx] = tile[tx][kl];
  }
}

// ---------- e_sq[k] = sum_d embed[d][k]^2 ----------
__global__ __launch_bounds__(256) void esq_kernel(const float* __restrict__ embed,
                                                  float* __restrict__ e_sq) {
  const int k = blockIdx.x * 256 + threadIdx.x;
  float s = 0.f;
  #pragma unroll 4
  for (int d = 0; d < DIM; ++d) {
    const float v = embed[(size_t)d * NEMB + k];
    s += v * v;
  }
  e_sq[k] = s;
}

// ---------- pack embed into MFMA B-fragment layout, bf16 hi/lo ----------
// epack chunk index = ((ct*8 + ks)*2 + p)*64 + l   (uint4 = 16B = 8 bf16)
// lane l of chunk holds B[k][n] for n = ct*16 + (l&15), k = ks*32 + (l>>4)*8 + j
__global__ __launch_bounds__(256) void pack_e_kernel(const float* __restrict__ embed,
                                                     uint4* __restrict__ epack) {
  const int t  = blockIdx.x * 256 + threadIdx.x;  // 0 .. 512*8*64-1
  const int l  = t & 63;
  const int ks = (t >> 6) & 7;
  const int ct = t >> 9;
  const int n     = ct * 16 + (l & 15);
  const int kbase = ks * 32 + (l >> 4) * 8;
  unsigned int h[4], lo[4];
  #pragma unroll
  for (int jj = 0; jj < 4; ++jj) {
    const float va = embed[(size_t)(kbase + 2 * jj) * NEMB + n];
    const float vb = embed[(size_t)(kbase + 2 * jj + 1) * NEMB + n];
    const unsigned short ha = f2bf_rne(va), hb = f2bf_rne(vb);
    const unsigned short la = f2bf_rne(va - bf2f(ha)), lb = f2bf_rne(vb - bf2f(hb));
    h[jj]  = (unsigned int)ha | ((unsigned int)hb << 16);
    lo[jj] = (unsigned int)la | ((unsigned int)lb << 16);
  }
  const size_t base = ((size_t)(ct * 8 + ks) * 2) * 64 + l;
  epack[base]      = make_uint4(h[0], h[1], h[2], h[3]);
  epack[base + 64] = make_uint4(lo[0], lo[1], lo[2], lo[3]);
}

// ---------- MFMA distance + per-row top-2 argmin ----------
// Block: 64 rows, 4 waves. x packed hi/lo into LDS A-frag layout (staged once).
// Wave w handles code tiles ct = cs*16 + w*4 + c over cs = 0..31.
__global__ __launch_bounds__(256, 2) void argmin_mfma_kernel(
    const float* __restrict__ x, const uint4* __restrict__ epack,
    const float* __restrict__ e_sq, int* __restrict__ out_i1, int* __restrict__ out_i2) {
  __shared__ uint4 xs[4 * 8 * 2 * 64];   // 64 KB: [rt][ks][p][lane] 16B chunks
  __shared__ float4 mbuf[4 * 64];        // 4 KB cross-wave merge

  const int tid  = threadIdx.x;
  const int lane = tid & 63;
  const int w    = tid >> 6;
  const int row0 = blockIdx.x * 64;
  const int quad = lane >> 4;
  const int lcol = lane & 15;

  // ---- stage + split x into LDS (A-frag layout) ----
  #pragma unroll
  for (int i = 0; i < 16; ++i) {
    const int g   = tid + 256 * i;       // float4 id within 64 rows x 64 float4s
    const int row = g >> 6;
    const int f4  = g & 63;
    const int k0  = f4 << 2;
    const float4 v = ((const float4*)(x + (size_t)(row0 + row) * DIM))[f4];
    const unsigned short h0 = f2bf_rne(v.x), h1 = f2bf_rne(v.y),
                         h2 = f2bf_rne(v.z), h3 = f2bf_rne(v.w);
    const unsigned short l0 = f2bf_rne(v.x - bf2f(h0)), l1 = f2bf_rne(v.y - bf2f(h1)),
                         l2 = f2bf_rne(v.z - bf2f(h2)), l3 = f2bf_rne(v.w - bf2f(h3));
    const int rt = row >> 4;
    const int ks = k0 >> 5;
    const int lp = (row & 15) + ((k0 & 31) >> 3) * 16;
    const int j0 = k0 & 7;              // 0 or 4
    unsigned short* bh = (unsigned short*)&xs[((rt * 8 + ks) * 2 + 0) * 64 + lp] + j0;
    unsigned short* bl = (unsigned short*)&xs[((rt * 8 + ks) * 2 + 1) * 64 + lp] + j0;
    *(uint2*)bh = make_uint2((unsigned int)h0 | ((unsigned int)h1 << 16),
                             (unsigned int)h2 | ((unsigned int)h3 << 16));
    *(uint2*)bl = make_uint2((unsigned int)l0 | ((unsigned int)l1 << 16),
                             (unsigned int)l2 | ((unsigned int)l3 << 16));
  }
  __syncthreads();

  float v1[16], v2[16];
  int   j1[16], j2[16];
  #pragma unroll
  for (int s = 0; s < 16; ++s) {
    v1[s] = __builtin_inff(); v2[s] = __builtin_inff();
    j1[s] = 0x7fffffff;       j2[s] = 0x7fffffff;
  }

  for (int cs = 0; cs < 32; ++cs) {
    f32x4 acc[4][4];
    #pragma unroll
    for (int rt = 0; rt < 4; ++rt)
      #pragma unroll
      for (int c = 0; c < 4; ++c) acc[rt][c] = (f32x4){0.f, 0.f, 0.f, 0.f};

    #pragma unroll
    for (int ks = 0; ks < 8; ++ks) {
      short8 ah[4], al[4];
      #pragma unroll
      for (int rt = 0; rt < 4; ++rt) {
        ah[rt] = *(const short8*)&xs[((rt * 8 + ks) * 2 + 0) * 64 + lane];
        al[rt] = *(const short8*)&xs[((rt * 8 + ks) * 2 + 1) * 64 + lane];
      }
      short8 bh[4], bl[4];
      #pragma unroll
      for (int c = 0; c < 4; ++c) {
        const int ct = cs * 16 + w * 4 + c;
        const uint4* p = epack + ((size_t)(ct * 8 + ks) * 2) * 64 + lane;
        bh[c] = *(const short8*)p;
        bl[c] = *(const short8*)(p + 64);
      }
      #pragma unroll
      for (int rt = 0; rt < 4; ++rt)
        #pragma unroll
        for (int c = 0; c < 4; ++c) {
          acc[rt][c] = __builtin_amdgcn_mfma_f32_16x16x32_bf16(ah[rt], bh[c], acc[rt][c], 0, 0, 0);
          acc[rt][c] = __builtin_amdgcn_mfma_f32_16x16x32_bf16(ah[rt], bl[c], acc[rt][c], 0, 0, 0);
          acc[rt][c] = __builtin_amdgcn_mfma_f32_16x16x32_bf16(al[rt], bh[c], acc[rt][c], 0, 0, 0);
        }
    }

    #pragma unroll
    for (int c = 0; c < 4; ++c) {
      const int col = cs * 256 + w * 64 + c * 16 + lcol;
      const float es = e_sq[col];
      #pragma unroll
      for (int rt = 0; rt < 4; ++rt)
        #pragma unroll
        for (int r = 0; r < 4; ++r) {
          const float d = es - 2.f * acc[rt][c][r];
          top2_update(v1[rt * 4 + r], j1[rt * 4 + r], v2[rt * 4 + r], j2[rt * 4 + r], d, col);
        }
    }
  }

  // ---- butterfly merge across the 16 lanes of each quad-group (same rows) ----
  #pragma unroll
  for (int s = 0; s < 16; ++s) {
    float a1 = v1[s], a2 = v2[s];
    int ia1 = j1[s], ia2 = j2[s];
    #pragma unroll
    for (int m = 1; m < 16; m <<= 1) {
      const float b1 = __shfl_xor(a1, m);
      const int  ib1 = __shfl_xor(ia1, m);
      const float b2 = __shfl_xor(a2, m);
      const int  ib2 = __shfl_xor(ia2, m);
      merge_top2(a1, ia1, a2, ia2, b1, ib1, b2, ib2);
    }
    v1[s] = a1; v2[s] = a2; j1[s] = ia1; j2[s] = ia2;
  }
  if (lcol == 0) {
    #pragma unroll
    for (int s = 0; s < 16; ++s) {
      const int rt = s >> 2, rr = s & 3;
      const int row = rt * 16 + quad * 4 + rr;
      mbuf[w * 64 + row] = make_float4(v1[s], __int_as_float(j1[s]),
                                       v2[s], __int_as_float(j2[s]));
    }
  }
  __syncthreads();

  if (tid < 64) {
    float4 e0 = mbuf[tid];
    float a1 = e0.x, a2 = e0.z;
    int ia1 = __float_as_int(e0.y), ia2 = __float_as_int(e0.w);
    #pragma unroll
    for (int ww = 1; ww < 4; ++ww) {
      const float4 e = mbuf[ww * 64 + tid];
      merge_top2(a1, ia1, a2, ia2, e.x, __float_as_int(e.y), e.z, __float_as_int(e.w));
    }
    out_i1[row0 + tid] = ia1;
    out_i2[row0 + tid] = ia2;
  }
}

// ---------- round-1 fp32 argmin (fallback if ws too small for epack) ----------
__global__ __launch_bounds__(256) void argmin_kernel(
    const float* __restrict__ x, const float* __restrict__ embed,
    const float* __restrict__ e_sq, int* __restrict__ out_i1, int* __restrict__ out_i2) {
  __shared__ float xsh[TM][DIM];
  __shared__ float rv1[4][TM], rv2[4][TM];
  __shared__ int   rj1[4][TM], rj2[4][TM];

  const int tid  = threadIdx.x;
  const int row0 = blockIdx.x * TM;
  {
    const float4* src = (const float4*)(x + (size_t)row0 * DIM);
    float4* dst = (float4*)xsh;
    #pragma unroll
    for (int i = 0; i < (TM * DIM / 4) / 256; ++i)
      dst[tid + 256 * i] = src[tid + 256 * i];
  }
  __syncthreads();

  float v1[TM], v2[TM];
  int   j1[TM], j2[TM];
  #pragma unroll
  for (int r = 0; r < TM; ++r) {
    v1[r] = __builtin_inff(); v2[r] = __builtin_inff();
    j1[r] = 0x7fffffff;       j2[r] = 0x7fffffff;
  }

  for (int c = 0; c < NEMB / (256 * TK); ++c) {
    const int k = c * (256 * TK) + tid * TK;
    float4 acc[TM];
    #pragma unroll
    for (int r = 0; r < TM; ++r) acc[r] = make_float4(0.f, 0.f, 0.f, 0.f);
    const float* eb = embed + k;
    #pragma unroll 2
    for (int d4 = 0; d4 < DIM / 4; ++d4) {
      const int d = d4 * 4;
      const float4 e0 = *(const float4*)(eb + (size_t)(d + 0) * NEMB);
      const float4 e1 = *(const float4*)(eb + (size_t)(d + 1) * NEMB);
      const float4 e2 = *(const float4*)(eb + (size_t)(d + 2) * NEMB);
      const float4 e3 = *(const float4*)(eb + (size_t)(d + 3) * NEMB);
      #pragma unroll
      for (int r = 0; r < TM; ++r) {
        const float4 xv = *(const float4*)&xsh[r][d];
        fma4(acc[r], xv.x, e0); fma4(acc[r], xv.y, e1);
        fma4(acc[r], xv.z, e2); fma4(acc[r], xv.w, e3);
      }
    }
    const float4 es = *(const float4*)(e_sq + k);
    #pragma unroll
    for (int r = 0; r < TM; ++r) {
      top2_update(v1[r], j1[r], v2[r], j2[r], es.x - 2.f * acc[r].x, k + 0);
      top2_update(v1[r], j1[r], v2[r], j2[r], es.y - 2.f * acc[r].y, k + 1);
      top2_update(v1[r], j1[r], v2[r], j2[r], es.z - 2.f * acc[r].z, k + 2);
      top2_update(v1[r], j1[r], v2[r], j2[r], es.w - 2.f * acc[r].w, k + 3);
    }
  }

  const int lane = tid & 63;
  const int wv   = tid >> 6;
  #pragma unroll
  for (int r = 0; r < TM; ++r) {
    float a1 = v1[r], a2 = v2[r];
    int ia1 = j1[r], ia2 = j2[r];
    #pragma unroll
    for (int m = 1; m < 64; m <<= 1) {
      const float b1 = __shfl_xor(a1, m);
      const int  ib1 = __shfl_xor(ia1, m);
      const float b2 = __shfl_xor(a2, m);
      const int  ib2 = __shfl_xor(ia2, m);
      merge_top2(a1, ia1, a2, ia2, b1, ib1, b2, ib2);
    }
    if (lane == 0) { rv1[wv][r] = a1; rv2[wv][r] = a2; rj1[wv][r] = ia1; rj2[wv][r] = ia2; }
  }
  __syncthreads();

  if (tid < TM) {
    float a1 = rv1[0][tid], a2 = rv2[0][tid];
    int ia1 = rj1[0][tid], ia2 = rj2[0][tid];
    #pragma unroll
    for (int w2 = 1; w2 < 4; ++w2)
      merge_top2(a1, ia1, a2, ia2, rv1[w2][tid], rj1[w2][tid], rv2[w2][tid], rj2[w2][tid]);
    out_i1[row0 + tid] = ia1;
    out_i2[row0 + tid] = ia2;
  }
}

// ---------- refine (fp64 decide between top-2) + gather ----------
template <bool USE_T>
__global__ __launch_bounds__(256) void refine_gather_kernel(
    const float* __restrict__ x, const float* __restrict__ embed,
    const float* __restrict__ embedT, const int* __restrict__ in_i1,
    const int* __restrict__ in_i2, float* __restrict__ out) {
  const int lane = threadIdx.x & 63;
  const int row  = blockIdx.x * (blockDim.x >> 6) + (threadIdx.x >> 6);
  const int k1 = in_i1[row];
  const int k2 = in_i2[row];

  const float4 xv = *(const float4*)(x + (size_t)row * DIM + lane * 4);
  float4 e1v, e2v;
  if (USE_T) {
    e1v = *(const float4*)(embedT + (size_t)k1 * DIM + lane * 4);
    e2v = *(const float4*)(embedT + (size_t)k2 * DIM + lane * 4);
  } else {
    const int d = lane * 4;
    e1v.x = embed[(size_t)(d + 0) * NEMB + k1]; e1v.y = embed[(size_t)(d + 1) * NEMB + k1];
    e1v.z = embed[(size_t)(d + 2) * NEMB + k1]; e1v.w = embed[(size_t)(d + 3) * NEMB + k1];
    e2v.x = embed[(size_t)(d + 0) * NEMB + k2]; e2v.y = embed[(size_t)(d + 1) * NEMB + k2];
    e2v.z = embed[(size_t)(d + 2) * NEMB + k2]; e2v.w = embed[(size_t)(d + 3) * NEMB + k2];
  }

  double dot1 = (double)xv.x * e1v.x + (double)xv.y * e1v.y +
                (double)xv.z * e1v.z + (double)xv.w * e1v.w;
  double dot2 = (double)xv.x * e2v.x + (double)xv.y * e2v.y +
                (double)xv.z * e2v.z + (double)xv.w * e2v.w;
  double q1 = (double)e1v.x * e1v.x + (double)e1v.y * e1v.y +
              (double)e1v.z * e1v.z + (double)e1v.w * e1v.w;
  double q2 = (double)e2v.x * e2v.x + (double)e2v.y * e2v.y +
              (double)e2v.z * e2v.z + (double)e2v.w * e2v.w;

  #pragma unroll
  for (int m = 1; m < 64; m <<= 1) {
    dot1 += __shfl_xor(dot1, m);
    dot2 += __shfl_xor(dot2, m);
    q1   += __shfl_xor(q1, m);
    q2   += __shfl_xor(q2, m);
  }

  const double dist1 = q1 - 2.0 * dot1;
  const double dist2 = q2 - 2.0 * dot2;
  const bool pick1 = (dist1 < dist2) || (dist1 == dist2 && k1 <= k2);
  *(float4*)(out + (size_t)row * DIM + lane * 4) = pick1 ? e1v : e2v;
}

// ---------- launch ----------
extern "C" void kernel_launch(void* const* d_in, const int* in_sizes, int n_in,
                              void* d_out, int out_size, void* d_ws, size_t ws_size,
                              hipStream_t stream) {
  const float* x     = (const float*)d_in[0];
  const float* embed = (const float*)d_in[1];
  float* out = (float*)d_out;

  char* ws = (char*)d_ws;
  const size_t embT_bytes  = (size_t)NEMB * DIM * sizeof(float);          // 8 MB
  const size_t epack_bytes = (size_t)NEMB * DIM * 2 * sizeof(short);      // 8 MB (hi+lo)
  const size_t esq_bytes   = (size_t)NEMB * sizeof(float);                // 32 KB
  const size_t idx_bytes   = (size_t)NROWS * sizeof(int);                 // 128 KB

  const bool mfma_path = ws_size >= embT_bytes + epack_bytes + esq_bytes + 2 * idx_bytes;
  const bool full      = ws_size >= embT_bytes + esq_bytes + 2 * idx_bytes;

  if (mfma_path) {
    float* embedT = (float*)ws;
    uint4* epack  = (uint4*)(ws + embT_bytes);
    float* e_sq   = (float*)(ws + embT_bytes + epack_bytes);
    int*   i1     = (int*)(ws + embT_bytes + epack_bytes + esq_bytes);
    int*   i2     = i1 + NROWS;

    transpose_kernel<<<dim3(NEMB / 64, DIM / 64), 256, 0, stream>>>(embed, embedT);
    esq_kernel<<<NEMB / 256, 256, 0, stream>>>(embed, e_sq);
    pack_e_kernel<<<(NEMB / 16) * 8 * 64 / 256, 256, 0, stream>>>(embed, epack);
    argmin_mfma_kernel<<<NROWS / 64, 256, 0, stream>>>(x, epack, e_sq, i1, i2);
    refine_gather_kernel<true><<<NROWS / 4, 256, 0, stream>>>(x, embed, embedT, i1, i2, out);
  } else if (full) {
    float* embedT = (float*)ws;
    float* e_sq   = (float*)(ws + embT_bytes);
    int*   i1     = (int*)(ws + embT_bytes + esq_bytes);
    int*   i2     = i1 + NROWS;
    transpose_kernel<<<dim3(NEMB / 64, DIM / 64), 256, 0, stream>>>(embed, embedT);
    esq_kernel<<<NEMB / 256, 256, 0, stream>>>(embed, e_sq);
    argmin_kernel<<<NROWS / TM, 256, 0, stream>>>(x, embed, e_sq, i1, i2);
    refine_gather_kernel<true><<<NROWS / 4, 256, 0, stream>>>(x, embed, embedT, i1, i2, out);
  } else {
    float* e_sq = (float*)ws;
    int*   i1   = (int*)(ws + esq_bytes);
    int*   i2   = i1 + NROWS;
    esq_kernel<<<NEMB / 256, 256, 0, stream>>>(embed, e_sq);
    argmin_kernel<<<NROWS / TM, 256, 0, stream>>>(x, embed, e_sq, i1, i2);
    refine_gather_kernel<false><<<NROWS / 4, 256, 0, stream>>>(x, embed, nullptr, i1, i2, out);
  }
}

// Round 4
// 1171.178 us; speedup vs baseline: 2.2004x; 1.4857x over previous
//
#include <hip/hip_runtime.h>
#include <cstddef>

#define DIM   256
#define NEMB  8192
#define NROWS 32768
#define TM    16
#define TK    4

typedef __attribute__((ext_vector_type(8))) short short8;
typedef __attribute__((ext_vector_type(4))) float f32x4;

// ---------- helpers ----------
__device__ __forceinline__ bool better(float va, int ia, float vb, int ib) {
  return (va < vb) || (va == vb && ia < ib);
}

// branchless top-2 (strict <; per-lane scan order has increasing k, so ties keep first)
__device__ __forceinline__ void top2_bl(float& v1, int& i1, float& v2, int& i2,
                                        float d, int k) {
  const bool b1 = d < v1;
  const bool b2 = d < v2;
  const float nv2 = b1 ? v1 : (b2 ? d : v2);
  const int   ni2 = b1 ? i1 : (b2 ? k : i2);
  v1 = b1 ? d : v1;
  i1 = b1 ? k : i1;
  v2 = nv2;
  i2 = ni2;
}

__device__ __forceinline__ void merge_top2(float& a1, int& ia1, float& a2, int& ia2,
                                           float b1, int ib1, float b2, int ib2) {
  if (better(b1, ib1, a1, ia1)) {
    if (better(b2, ib2, a1, ia1)) { a1 = b1; ia1 = ib1; a2 = b2; ia2 = ib2; }
    else                          { a2 = a1; ia2 = ia1; a1 = b1; ia1 = ib1; }
  } else {
    if (better(b1, ib1, a2, ia2)) { a2 = b1; ia2 = ib1; }
  }
}

__device__ __forceinline__ void fma4(float4& a, float s, const float4& b) {
  a.x += s * b.x; a.y += s * b.y; a.z += s * b.z; a.w += s * b.w;
}

__device__ __forceinline__ unsigned short f2bf_rne(float f) {
  unsigned int u = __float_as_uint(f);
  u += 0x7FFFu + ((u >> 16) & 1u);
  return (unsigned short)(u >> 16);
}
__device__ __forceinline__ float bf2f(unsigned short h) {
  return __uint_as_float(((unsigned int)h) << 16);
}

// ---------- transpose: embedT[k*DIM + d] = embed[d*NEMB + k] ----------
__global__ __launch_bounds__(256) void transpose_kernel(const float* __restrict__ embed,
                                                        float* __restrict__ embedT) {
  __shared__ float tile[64][65];
  const int tx = threadIdx.x & 63;
  const int ty = threadIdx.x >> 6;
  const int k0 = blockIdx.x * 64;
  const int d0 = blockIdx.y * 64;
  #pragma unroll
  for (int i = 0; i < 16; ++i) {
    const int dl = ty + i * 4;
    tile[dl][tx] = embed[(size_t)(d0 + dl) * NEMB + k0 + tx];
  }
  __syncthreads();
  #pragma unroll
  for (int i = 0; i < 16; ++i) {
    const int kl = ty + i * 4;
    embedT[(size_t)(k0 + kl) * DIM + d0 + tx] = tile[tx][kl];
  }
}

// ---------- e_sq[k] = sum_d embed[d][k]^2 ----------
__global__ __launch_bounds__(256) void esq_kernel(const float* __restrict__ embed,
                                                  float* __restrict__ e_sq) {
  const int k = blockIdx.x * 256 + threadIdx.x;
  float s = 0.f;
  #pragma unroll 4
  for (int d = 0; d < DIM; ++d) {
    const float v = embed[(size_t)d * NEMB + k];
    s += v * v;
  }
  e_sq[k] = s;
}

// ---------- pack (-2*embed) into MFMA B-fragment layout, bf16 hi/lo ----------
// chunk index = ((ct*8 + ks)*2 + p)*64 + l  (uint4 = 8 bf16)
// lane l holds B[k][n] for n = ct*16 + (l&15), k = ks*32 + (l>>4)*8 + j
__global__ __launch_bounds__(256) void pack_e_kernel(const float* __restrict__ embed,
                                                     uint4* __restrict__ epack) {
  const int t  = blockIdx.x * 256 + threadIdx.x;
  const int l  = t & 63;
  const int ks = (t >> 6) & 7;
  const int ct = t >> 9;
  const int n     = ct * 16 + (l & 15);
  const int kbase = ks * 32 + (l >> 4) * 8;
  unsigned int h[4], lo[4];
  #pragma unroll
  for (int jj = 0; jj < 4; ++jj) {
    const float va = -2.f * embed[(size_t)(kbase + 2 * jj) * NEMB + n];
    const float vb = -2.f * embed[(size_t)(kbase + 2 * jj + 1) * NEMB + n];
    const unsigned short ha = f2bf_rne(va), hb = f2bf_rne(vb);
    const unsigned short la = f2bf_rne(va - bf2f(ha)), lb = f2bf_rne(vb - bf2f(hb));
    h[jj]  = (unsigned int)ha | ((unsigned int)hb << 16);
    lo[jj] = (unsigned int)la | ((unsigned int)lb << 16);
  }
  const size_t base = ((size_t)(ct * 8 + ks) * 2) * 64 + l;
  epack[base]      = make_uint4(h[0], h[1], h[2], h[3]);
  epack[base + 64] = make_uint4(lo[0], lo[1], lo[2], lo[3]);
}

// ---------- MFMA distance + per-row top-2 argmin ----------
// Round-2 structure (64 rows/block staged in LDS, 4 waves split the codebook
// 4-way -> every code seen exactly once per block), spill-fixed:
// branchless top-2 + 2 code-tiles in flight (acc 32 regs, B-frags 16 regs).
__global__ __launch_bounds__(256, 2) void argmin_mfma_kernel(
    const float* __restrict__ x, const uint4* __restrict__ epack,
    const float* __restrict__ e_sq, int* __restrict__ out_i1, int* __restrict__ out_i2) {
  __shared__ uint4 xs[4 * 8 * 2 * 64];   // 64 KB: [rt][ks][p][lane] 16B chunks
  __shared__ float4 mbuf[4 * 64];        // 4 KB cross-wave merge

  const int tid  = threadIdx.x;
  const int lane = tid & 63;
  const int w    = tid >> 6;
  const int row0 = blockIdx.x * 64;
  const int quad = lane >> 4;
  const int lcol = lane & 15;

  // ---- stage + split x into LDS (A-frag layout, hw-verified in round 2) ----
  #pragma unroll
  for (int i = 0; i < 16; ++i) {
    const int g   = tid + 256 * i;       // float4 id within 64 rows x 64 float4s
    const int row = g >> 6;
    const int f4  = g & 63;
    const int k0  = f4 << 2;
    const float4 v = ((const float4*)(x + (size_t)(row0 + row) * DIM))[f4];
    const unsigned short h0 = f2bf_rne(v.x), h1 = f2bf_rne(v.y),
                         h2 = f2bf_rne(v.z), h3 = f2bf_rne(v.w);
    const unsigned short l0 = f2bf_rne(v.x - bf2f(h0)), l1 = f2bf_rne(v.y - bf2f(h1)),
                         l2 = f2bf_rne(v.z - bf2f(h2)), l3 = f2bf_rne(v.w - bf2f(h3));
    const int rt = row >> 4;
    const int ks = k0 >> 5;
    const int lp = (row & 15) + ((k0 & 31) >> 3) * 16;
    const int j0 = k0 & 7;              // 0 or 4
    unsigned short* bh = (unsigned short*)&xs[((rt * 8 + ks) * 2 + 0) * 64 + lp] + j0;
    unsigned short* bl = (unsigned short*)&xs[((rt * 8 + ks) * 2 + 1) * 64 + lp] + j0;
    *(uint2*)bh = make_uint2((unsigned int)h0 | ((unsigned int)h1 << 16),
                             (unsigned int)h2 | ((unsigned int)h3 << 16));
    *(uint2*)bl = make_uint2((unsigned int)l0 | ((unsigned int)l1 << 16),
                             (unsigned int)l2 | ((unsigned int)l3 << 16));
  }
  __syncthreads();

  float v1[16], v2[16];
  int   j1[16], j2[16];
  #pragma unroll
  for (int s = 0; s < 16; ++s) {
    v1[s] = __builtin_inff(); v2[s] = __builtin_inff();
    j1[s] = 0x7fffffff;       j2[s] = 0x7fffffff;
  }

  // wave w covers tiles ct = cs*16 + w*4 + {0..3}, cs = 0..31 -> all 8192 codes/block
  for (int cs = 0; cs < 32; ++cs) {
    #pragma unroll
    for (int half = 0; half < 2; ++half) {
      const int ct0 = cs * 16 + w * 4 + half * 2;   // 2 tiles in flight
      // prefetch e_sq early (hidden behind MFMAs)
      const float es0 = e_sq[(ct0 + 0) * 16 + lcol];
      const float es1 = e_sq[(ct0 + 1) * 16 + lcol];

      f32x4 acc[4][2];
      #pragma unroll
      for (int rt = 0; rt < 4; ++rt)
        #pragma unroll
        for (int c = 0; c < 2; ++c) acc[rt][c] = (f32x4){0.f, 0.f, 0.f, 0.f};

      #pragma unroll
      for (int ks = 0; ks < 8; ++ks) {
        short8 bh[2], bl[2];
        #pragma unroll
        for (int c = 0; c < 2; ++c) {
          const uint4* p = epack + (((size_t)(ct0 + c) * 8 + ks) * 2) * 64 + lane;
          bh[c] = *(const short8*)p;
          bl[c] = *(const short8*)(p + 64);
        }
        #pragma unroll
        for (int rt = 0; rt < 4; ++rt) {
          const short8 ah = *(const short8*)&xs[((rt * 8 + ks) * 2 + 0) * 64 + lane];
          const short8 al = *(const short8*)&xs[((rt * 8 + ks) * 2 + 1) * 64 + lane];
          #pragma unroll
          for (int c = 0; c < 2; ++c) {
            acc[rt][c] = __builtin_amdgcn_mfma_f32_16x16x32_bf16(ah, bh[c], acc[rt][c], 0, 0, 0);
            acc[rt][c] = __builtin_amdgcn_mfma_f32_16x16x32_bf16(al, bh[c], acc[rt][c], 0, 0, 0);
            acc[rt][c] = __builtin_amdgcn_mfma_f32_16x16x32_bf16(ah, bl[c], acc[rt][c], 0, 0, 0);
          }
        }
      }

      // acc = -2*dot  ->  dist = e_sq + acc
      #pragma unroll
      for (int c = 0; c < 2; ++c) {
        const int col = (ct0 + c) * 16 + lcol;
        const float es = (c == 0) ? es0 : es1;
        #pragma unroll
        for (int rt = 0; rt < 4; ++rt)
          #pragma unroll
          for (int r = 0; r < 4; ++r) {
            const float d = es + acc[rt][c][r];
            top2_bl(v1[rt * 4 + r], j1[rt * 4 + r], v2[rt * 4 + r], j2[rt * 4 + r], d, col);
          }
      }
    }
  }

  // ---- butterfly merge across the 16 lanes of each quad-group (same rows) ----
  #pragma unroll
  for (int s = 0; s < 16; ++s) {
    float a1 = v1[s], a2 = v2[s];
    int ia1 = j1[s], ia2 = j2[s];
    #pragma unroll
    for (int m = 1; m < 16; m <<= 1) {
      const float b1 = __shfl_xor(a1, m);
      const int  ib1 = __shfl_xor(ia1, m);
      const float b2 = __shfl_xor(a2, m);
      const int  ib2 = __shfl_xor(ia2, m);
      merge_top2(a1, ia1, a2, ia2, b1, ib1, b2, ib2);
    }
    v1[s] = a1; v2[s] = a2; j1[s] = ia1; j2[s] = ia2;
  }
  if (lcol == 0) {
    #pragma unroll
    for (int s = 0; s < 16; ++s) {
      const int rt = s >> 2, rr = s & 3;
      const int row = rt * 16 + quad * 4 + rr;
      mbuf[w * 64 + row] = make_float4(v1[s], __int_as_float(j1[s]),
                                       v2[s], __int_as_float(j2[s]));
    }
  }
  __syncthreads();

  if (tid < 64) {
    float4 e0 = mbuf[tid];
    float a1 = e0.x, a2 = e0.z;
    int ia1 = __float_as_int(e0.y), ia2 = __float_as_int(e0.w);
    #pragma unroll
    for (int ww = 1; ww < 4; ++ww) {
      const float4 e = mbuf[ww * 64 + tid];
      merge_top2(a1, ia1, a2, ia2, e.x, __float_as_int(e.y), e.z, __float_as_int(e.w));
    }
    out_i1[row0 + tid] = ia1;
    out_i2[row0 + tid] = ia2;
  }
}

// ---------- round-1 fp32 argmin (fallback if ws too small for epack) ----------
__global__ __launch_bounds__(256) void argmin_kernel(
    const float* __restrict__ x, const float* __restrict__ embed,
    const float* __restrict__ e_sq, int* __restrict__ out_i1, int* __restrict__ out_i2) {
  __shared__ float xsh[TM][DIM];
  __shared__ float rv1[4][TM], rv2[4][TM];
  __shared__ int   rj1[4][TM], rj2[4][TM];

  const int tid  = threadIdx.x;
  const int row0 = blockIdx.x * TM;
  {
    const float4* src = (const float4*)(x + (size_t)row0 * DIM);
    float4* dst = (float4*)xsh;
    #pragma unroll
    for (int i = 0; i < (TM * DIM / 4) / 256; ++i)
      dst[tid + 256 * i] = src[tid + 256 * i];
  }
  __syncthreads();

  float v1[TM], v2[TM];
  int   j1[TM], j2[TM];
  #pragma unroll
  for (int r = 0; r < TM; ++r) {
    v1[r] = __builtin_inff(); v2[r] = __builtin_inff();
    j1[r] = 0x7fffffff;       j2[r] = 0x7fffffff;
  }

  for (int c = 0; c < NEMB / (256 * TK); ++c) {
    const int k = c * (256 * TK) + tid * TK;
    float4 acc[TM];
    #pragma unroll
    for (int r = 0; r < TM; ++r) acc[r] = make_float4(0.f, 0.f, 0.f, 0.f);
    const float* eb = embed + k;
    #pragma unroll 2
    for (int d4 = 0; d4 < DIM / 4; ++d4) {
      const int d = d4 * 4;
      const float4 e0 = *(const float4*)(eb + (size_t)(d + 0) * NEMB);
      const float4 e1 = *(const float4*)(eb + (size_t)(d + 1) * NEMB);
      const float4 e2 = *(const float4*)(eb + (size_t)(d + 2) * NEMB);
      const float4 e3 = *(const float4*)(eb + (size_t)(d + 3) * NEMB);
      #pragma unroll
      for (int r = 0; r < TM; ++r) {
        const float4 xv = *(const float4*)&xsh[r][d];
        fma4(acc[r], xv.x, e0); fma4(acc[r], xv.y, e1);
        fma4(acc[r], xv.z, e2); fma4(acc[r], xv.w, e3);
      }
    }
    const float4 es = *(const float4*)(e_sq + k);
    #pragma unroll
    for (int r = 0; r < TM; ++r) {
      top2_bl(v1[r], j1[r], v2[r], j2[r], es.x - 2.f * acc[r].x, k + 0);
      top2_bl(v1[r], j1[r], v2[r], j2[r], es.y - 2.f * acc[r].y, k + 1);
      top2_bl(v1[r], j1[r], v2[r], j2[r], es.z - 2.f * acc[r].z, k + 2);
      top2_bl(v1[r], j1[r], v2[r], j2[r], es.w - 2.f * acc[r].w, k + 3);
    }
  }

  const int lane = tid & 63;
  const int wv   = tid >> 6;
  #pragma unroll
  for (int r = 0; r < TM; ++r) {
    float a1 = v1[r], a2 = v2[r];
    int ia1 = j1[r], ia2 = j2[r];
    #pragma unroll
    for (int m = 1; m < 64; m <<= 1) {
      const float b1 = __shfl_xor(a1, m);
      const int  ib1 = __shfl_xor(ia1, m);
      const float b2 = __shfl_xor(a2, m);
      const int  ib2 = __shfl_xor(ia2, m);
      merge_top2(a1, ia1, a2, ia2, b1, ib1, b2, ib2);
    }
    if (lane == 0) { rv1[wv][r] = a1; rv2[wv][r] = a2; rj1[wv][r] = ia1; rj2[wv][r] = ia2; }
  }
  __syncthreads();

  if (tid < TM) {
    float a1 = rv1[0][tid], a2 = rv2[0][tid];
    int ia1 = rj1[0][tid], ia2 = rj2[0][tid];
    #pragma unroll
    for (int w2 = 1; w2 < 4; ++w2)
      merge_top2(a1, ia1, a2, ia2, rv1[w2][tid], rj1[w2][tid], rv2[w2][tid], rj2[w2][tid]);
    out_i1[row0 + tid] = ia1;
    out_i2[row0 + tid] = ia2;
  }
}

// ---------- refine (fp64 decide between top-2) + gather ----------
template <bool USE_T>
__global__ __launch_bounds__(256) void refine_gather_kernel(
    const float* __restrict__ x, const float* __restrict__ embed,
    const float* __restrict__ embedT, const int* __restrict__ in_i1,
    const int* __restrict__ in_i2, float* __restrict__ out) {
  const int lane = threadIdx.x & 63;
  const int row  = blockIdx.x * (blockDim.x >> 6) + (threadIdx.x >> 6);
  const int k1 = in_i1[row];
  const int k2 = in_i2[row];

  const float4 xv = *(const float4*)(x + (size_t)row * DIM + lane * 4);
  float4 e1v, e2v;
  if (USE_T) {
    e1v = *(const float4*)(embedT + (size_t)k1 * DIM + lane * 4);
    e2v = *(const float4*)(embedT + (size_t)k2 * DIM + lane * 4);
  } else {
    const int d = lane * 4;
    e1v.x = embed[(size_t)(d + 0) * NEMB + k1]; e1v.y = embed[(size_t)(d + 1) * NEMB + k1];
    e1v.z = embed[(size_t)(d + 2) * NEMB + k1]; e1v.w = embed[(size_t)(d + 3) * NEMB + k1];
    e2v.x = embed[(size_t)(d + 0) * NEMB + k2]; e2v.y = embed[(size_t)(d + 1) * NEMB + k2];
    e2v.z = embed[(size_t)(d + 2) * NEMB + k2]; e2v.w = embed[(size_t)(d + 3) * NEMB + k2];
  }

  double dot1 = (double)xv.x * e1v.x + (double)xv.y * e1v.y +
                (double)xv.z * e1v.z + (double)xv.w * e1v.w;
  double dot2 = (double)xv.x * e2v.x + (double)xv.y * e2v.y +
                (double)xv.z * e2v.z + (double)xv.w * e2v.w;
  double q1 = (double)e1v.x * e1v.x + (double)e1v.y * e1v.y +
              (double)e1v.z * e1v.z + (double)e1v.w * e1v.w;
  double q2 = (double)e2v.x * e2v.x + (double)e2v.y * e2v.y +
              (double)e2v.z * e2v.z + (double)e2v.w * e2v.w;

  #pragma unroll
  for (int m = 1; m < 64; m <<= 1) {
    dot1 += __shfl_xor(dot1, m);
    dot2 += __shfl_xor(dot2, m);
    q1   += __shfl_xor(q1, m);
    q2   += __shfl_xor(q2, m);
  }

  const double dist1 = q1 - 2.0 * dot1;
  const double dist2 = q2 - 2.0 * dot2;
  const bool pick1 = (dist1 < dist2) || (dist1 == dist2 && k1 <= k2);
  *(float4*)(out + (size_t)row * DIM + lane * 4) = pick1 ? e1v : e2v;
}

// ---------- launch ----------
extern "C" void kernel_launch(void* const* d_in, const int* in_sizes, int n_in,
                              void* d_out, int out_size, void* d_ws, size_t ws_size,
                              hipStream_t stream) {
  const float* x     = (const float*)d_in[0];
  const float* embed = (const float*)d_in[1];
  float* out = (float*)d_out;

  char* ws = (char*)d_ws;
  const size_t embT_bytes  = (size_t)NEMB * DIM * sizeof(float);          // 8 MB
  const size_t epack_bytes = (size_t)NEMB * DIM * 2 * sizeof(short);      // 8 MB (hi+lo)
  const size_t esq_bytes   = (size_t)NEMB * sizeof(float);                // 32 KB
  const size_t idx_bytes   = (size_t)NROWS * sizeof(int);                 // 128 KB

  const bool mfma_path = ws_size >= embT_bytes + epack_bytes + esq_bytes + 2 * idx_bytes;
  const bool full      = ws_size >= embT_bytes + esq_bytes + 2 * idx_bytes;

  if (mfma_path) {
    float* embedT = (float*)ws;
    uint4* epack  = (uint4*)(ws + embT_bytes);
    float* e_sq   = (float*)(ws + embT_bytes + epack_bytes);
    int*   i1     = (int*)(ws + embT_bytes + epack_bytes + esq_bytes);
    int*   i2     = i1 + NROWS;

    transpose_kernel<<<dim3(NEMB / 64, DIM / 64), 256, 0, stream>>>(embed, embedT);
    esq_kernel<<<NEMB / 256, 256, 0, stream>>>(embed, e_sq);
    pack_e_kernel<<<(NEMB / 16) * 8 * 64 / 256, 256, 0, stream>>>(embed, epack);
    argmin_mfma_kernel<<<NROWS / 64, 256, 0, stream>>>(x, epack, e_sq, i1, i2);
    refine_gather_kernel<true><<<NROWS / 4, 256, 0, stream>>>(x, embed, embedT, i1, i2, out);
  } else if (full) {
    float* embedT = (float*)ws;
    float* e_sq   = (float*)(ws + embT_bytes);
    int*   i1     = (int*)(ws + embT_bytes + esq_bytes);
    int*   i2     = i1 + NROWS;
    transpose_kernel<<<dim3(NEMB / 64, DIM / 64), 256, 0, stream>>>(embed, embedT);
    esq_kernel<<<NEMB / 256, 256, 0, stream>>>(embed, e_sq);
    argmin_kernel<<<NROWS / TM, 256, 0, stream>>>(x, embed, e_sq, i1, i2);
    refine_gather_kernel<true><<<NROWS / 4, 256, 0, stream>>>(x, embed, embedT, i1, i2, out);
  } else {
    float* e_sq = (float*)ws;
    int*   i1   = (int*)(ws + esq_bytes);
    int*   i2   = i1 + NROWS;
    esq_kernel<<<NEMB / 256, 256, 0, stream>>>(embed, e_sq);
    argmin_kernel<<<NROWS / TM, 256, 0, stream>>>(x, embed, e_sq, i1, i2);
    refine_gather_kernel<false><<<NROWS / 4, 256, 0, stream>>>(x, embed, nullptr, i1, i2, out);
  }
}

// Round 5
// 1043.522 us; speedup vs baseline: 2.4695x; 1.1223x over previous
//
#include <hip/hip_runtime.h>
#include <cstddef>

#define DIM   256
#define NEMB  8192
#define NROWS 32768
#define NCHUNK 8              // code chunks, XCD-aligned via blockIdx&7
#define TM    16
#define TK    4

typedef __attribute__((ext_vector_type(8))) short short8;
typedef __attribute__((ext_vector_type(4))) float f32x4;

// ---------- helpers ----------
__device__ __forceinline__ bool better(float va, int ia, float vb, int ib) {
  return (va < vb) || (va == vb && ia < ib);
}

// branchless top-2 (strict <; per-lane scan order has increasing k, so ties keep first)
__device__ __forceinline__ void top2_bl(float& v1, int& i1, float& v2, int& i2,
                                        float d, int k) {
  const bool b1 = d < v1;
  const bool b2 = d < v2;
  const float nv2 = b1 ? v1 : (b2 ? d : v2);
  const int   ni2 = b1 ? i1 : (b2 ? k : i2);
  v1 = b1 ? d : v1;
  i1 = b1 ? k : i1;
  v2 = nv2;
  i2 = ni2;
}

__device__ __forceinline__ void merge_top2(float& a1, int& ia1, float& a2, int& ia2,
                                           float b1, int ib1, float b2, int ib2) {
  if (better(b1, ib1, a1, ia1)) {
    if (better(b2, ib2, a1, ia1)) { a1 = b1; ia1 = ib1; a2 = b2; ia2 = ib2; }
    else                          { a2 = a1; ia2 = ia1; a1 = b1; ia1 = ib1; }
  } else {
    if (better(b1, ib1, a2, ia2)) { a2 = b1; ia2 = ib1; }
  }
}

__device__ __forceinline__ void fma4(float4& a, float s, const float4& b) {
  a.x += s * b.x; a.y += s * b.y; a.z += s * b.z; a.w += s * b.w;
}

__device__ __forceinline__ unsigned short f2bf_rne(float f) {
  unsigned int u = __float_as_uint(f);
  u += 0x7FFFu + ((u >> 16) & 1u);
  return (unsigned short)(u >> 16);
}
__device__ __forceinline__ float bf2f(unsigned short h) {
  return __uint_as_float(((unsigned int)h) << 16);
}

// ---------- transpose: embedT[k*DIM + d] = embed[d*NEMB + k] ----------
__global__ __launch_bounds__(256) void transpose_kernel(const float* __restrict__ embed,
                                                        float* __restrict__ embedT) {
  __shared__ float tile[64][65];
  const int tx = threadIdx.x & 63;
  const int ty = threadIdx.x >> 6;
  const int k0 = blockIdx.x * 64;
  const int d0 = blockIdx.y * 64;
  #pragma unroll
  for (int i = 0; i < 16; ++i) {
    const int dl = ty + i * 4;
    tile[dl][tx] = embed[(size_t)(d0 + dl) * NEMB + k0 + tx];
  }
  __syncthreads();
  #pragma unroll
  for (int i = 0; i < 16; ++i) {
    const int kl = ty + i * 4;
    embedT[(size_t)(k0 + kl) * DIM + d0 + tx] = tile[tx][kl];
  }
}

// ---------- e_sq[k] = sum_d embed[d][k]^2 ----------
__global__ __launch_bounds__(256) void esq_kernel(const float* __restrict__ embed,
                                                  float* __restrict__ e_sq) {
  const int k = blockIdx.x * 256 + threadIdx.x;
  float s = 0.f;
  #pragma unroll 4
  for (int d = 0; d < DIM; ++d) {
    const float v = embed[(size_t)d * NEMB + k];
    s += v * v;
  }
  e_sq[k] = s;
}

// ---------- pack (-2*embed) into MFMA B-fragment layout, bf16 hi/lo ----------
// chunk index = ((ct*8 + ks)*2 + p)*64 + l  (uint4 = 8 bf16)
// lane l holds B[k][n] for n = ct*16 + (l&15), k = ks*32 + (l>>4)*8 + j
__global__ __launch_bounds__(256) void pack_e_kernel(const float* __restrict__ embed,
                                                     uint4* __restrict__ epack) {
  const int t  = blockIdx.x * 256 + threadIdx.x;
  const int l  = t & 63;
  const int ks = (t >> 6) & 7;
  const int ct = t >> 9;
  const int n     = ct * 16 + (l & 15);
  const int kbase = ks * 32 + (l >> 4) * 8;
  unsigned int h[4], lo[4];
  #pragma unroll
  for (int jj = 0; jj < 4; ++jj) {
    const float va = -2.f * embed[(size_t)(kbase + 2 * jj) * NEMB + n];
    const float vb = -2.f * embed[(size_t)(kbase + 2 * jj + 1) * NEMB + n];
    const unsigned short ha = f2bf_rne(va), hb = f2bf_rne(vb);
    const unsigned short la = f2bf_rne(va - bf2f(ha)), lb = f2bf_rne(vb - bf2f(hb));
    h[jj]  = (unsigned int)ha | ((unsigned int)hb << 16);
    lo[jj] = (unsigned int)la | ((unsigned int)lb << 16);
  }
  const size_t base = ((size_t)(ct * 8 + ks) * 2) * 64 + l;
  epack[base]      = make_uint4(h[0], h[1], h[2], h[3]);
  epack[base + 64] = make_uint4(lo[0], lo[1], lo[2], lo[3]);
}

// ---------- MFMA distance + per-row top-2 argmin, XCD-phased chunks ----------
// Grid = 4096 blocks: block b -> rows [(b>>3)*64, +64), code chunk cc = b&7
// (1024 codes = 1 MB of epack, L2-resident per XCD under round-robin dispatch).
// 4 waves split the chunk's 64 tiles 4-way; partial top-2 per (chunk,row) to ws.
__global__ __launch_bounds__(256, 1) void argmin_mfma_kernel(
    const float* __restrict__ x, const uint4* __restrict__ epack,
    const float* __restrict__ e_sq, float4* __restrict__ partial) {
  __shared__ uint4 xs[4 * 8 * 2 * 64];   // 64 KB: [rt][ks][p][lane] 16B chunks
  __shared__ float4 mbuf[4 * 64];        // 4 KB cross-wave merge

  const int tid  = threadIdx.x;
  const int lane = tid & 63;
  const int w    = tid >> 6;
  const int cc   = blockIdx.x & 7;
  const int row0 = (blockIdx.x >> 3) * 64;
  const int quad = lane >> 4;
  const int lcol = lane & 15;

  // ---- stage + split x into LDS (A-frag layout, hw-verified rounds 2/4) ----
  #pragma unroll
  for (int i = 0; i < 16; ++i) {
    const int g   = tid + 256 * i;       // float4 id within 64 rows x 64 float4s
    const int row = g >> 6;
    const int f4  = g & 63;
    const int k0  = f4 << 2;
    const float4 v = ((const float4*)(x + (size_t)(row0 + row) * DIM))[f4];
    const unsigned short h0 = f2bf_rne(v.x), h1 = f2bf_rne(v.y),
                         h2 = f2bf_rne(v.z), h3 = f2bf_rne(v.w);
    const unsigned short l0 = f2bf_rne(v.x - bf2f(h0)), l1 = f2bf_rne(v.y - bf2f(h1)),
                         l2 = f2bf_rne(v.z - bf2f(h2)), l3 = f2bf_rne(v.w - bf2f(h3));
    const int rt = row >> 4;
    const int ks = k0 >> 5;
    const int lp = (row & 15) + ((k0 & 31) >> 3) * 16;
    const int j0 = k0 & 7;              // 0 or 4
    unsigned short* bh = (unsigned short*)&xs[((rt * 8 + ks) * 2 + 0) * 64 + lp] + j0;
    unsigned short* bl = (unsigned short*)&xs[((rt * 8 + ks) * 2 + 1) * 64 + lp] + j0;
    *(uint2*)bh = make_uint2((unsigned int)h0 | ((unsigned int)h1 << 16),
                             (unsigned int)h2 | ((unsigned int)h3 << 16));
    *(uint2*)bl = make_uint2((unsigned int)l0 | ((unsigned int)l1 << 16),
                             (unsigned int)l2 | ((unsigned int)l3 << 16));
  }
  __syncthreads();

  float v1[16], v2[16];
  int   j1[16], j2[16];
  #pragma unroll
  for (int s = 0; s < 16; ++s) {
    v1[s] = __builtin_inff(); v2[s] = __builtin_inff();
    j1[s] = 0x7fffffff;       j2[s] = 0x7fffffff;
  }

  // chunk cc covers tiles [cc*64, (cc+1)*64); wave w takes cs*16 + w*4 + {0..3}
  for (int cs = 0; cs < 4; ++cs) {
    #pragma unroll
    for (int half = 0; half < 2; ++half) {
      const int ct0 = cc * 64 + cs * 16 + w * 4 + half * 2;   // 2 tiles in flight
      const float es0 = e_sq[(ct0 + 0) * 16 + lcol];
      const float es1 = e_sq[(ct0 + 1) * 16 + lcol];

      f32x4 acc[4][2];
      #pragma unroll
      for (int rt = 0; rt < 4; ++rt)
        #pragma unroll
        for (int c = 0; c < 2; ++c) acc[rt][c] = (f32x4){0.f, 0.f, 0.f, 0.f};

      #pragma unroll
      for (int ks = 0; ks < 8; ++ks) {
        short8 bh[2], bl[2];
        #pragma unroll
        for (int c = 0; c < 2; ++c) {
          const uint4* p = epack + (((size_t)(ct0 + c) * 8 + ks) * 2) * 64 + lane;
          bh[c] = *(const short8*)p;
          bl[c] = *(const short8*)(p + 64);
        }
        #pragma unroll
        for (int rt = 0; rt < 4; ++rt) {
          const short8 ah = *(const short8*)&xs[((rt * 8 + ks) * 2 + 0) * 64 + lane];
          const short8 al = *(const short8*)&xs[((rt * 8 + ks) * 2 + 1) * 64 + lane];
          #pragma unroll
          for (int c = 0; c < 2; ++c) {
            acc[rt][c] = __builtin_amdgcn_mfma_f32_16x16x32_bf16(ah, bh[c], acc[rt][c], 0, 0, 0);
            acc[rt][c] = __builtin_amdgcn_mfma_f32_16x16x32_bf16(al, bh[c], acc[rt][c], 0, 0, 0);
            acc[rt][c] = __builtin_amdgcn_mfma_f32_16x16x32_bf16(ah, bl[c], acc[rt][c], 0, 0, 0);
          }
        }
      }

      // acc = -2*dot  ->  dist = e_sq + acc
      #pragma unroll
      for (int c = 0; c < 2; ++c) {
        const int col = (ct0 + c) * 16 + lcol;
        const float es = (c == 0) ? es0 : es1;
        #pragma unroll
        for (int rt = 0; rt < 4; ++rt)
          #pragma unroll
          for (int r = 0; r < 4; ++r) {
            const float d = es + acc[rt][c][r];
            top2_bl(v1[rt * 4 + r], j1[rt * 4 + r], v2[rt * 4 + r], j2[rt * 4 + r], d, col);
          }
      }
    }
  }

  // ---- butterfly merge across the 16 lanes of each quad-group (same rows) ----
  #pragma unroll
  for (int s = 0; s < 16; ++s) {
    float a1 = v1[s], a2 = v2[s];
    int ia1 = j1[s], ia2 = j2[s];
    #pragma unroll
    for (int m = 1; m < 16; m <<= 1) {
      const float b1 = __shfl_xor(a1, m);
      const int  ib1 = __shfl_xor(ia1, m);
      const float b2 = __shfl_xor(a2, m);
      const int  ib2 = __shfl_xor(ia2, m);
      merge_top2(a1, ia1, a2, ia2, b1, ib1, b2, ib2);
    }
    v1[s] = a1; v2[s] = a2; j1[s] = ia1; j2[s] = ia2;
  }
  if (lcol == 0) {
    #pragma unroll
    for (int s = 0; s < 16; ++s) {
      const int rt = s >> 2, rr = s & 3;
      const int row = rt * 16 + quad * 4 + rr;
      mbuf[w * 64 + row] = make_float4(v1[s], __int_as_float(j1[s]),
                                       v2[s], __int_as_float(j2[s]));
    }
  }
  __syncthreads();

  if (tid < 64) {
    float4 e0 = mbuf[tid];
    float a1 = e0.x, a2 = e0.z;
    int ia1 = __float_as_int(e0.y), ia2 = __float_as_int(e0.w);
    #pragma unroll
    for (int ww = 1; ww < 4; ++ww) {
      const float4 e = mbuf[ww * 64 + tid];
      merge_top2(a1, ia1, a2, ia2, e.x, __float_as_int(e.y), e.z, __float_as_int(e.w));
    }
    partial[(size_t)cc * NROWS + row0 + tid] =
        make_float4(a1, __int_as_float(ia1), a2, __int_as_float(ia2));
  }
}

// ---------- merge 8 chunk-partials + fp64 refine + gather ----------
template <bool USE_T>
__global__ __launch_bounds__(256) void merge_refine_kernel(
    const float* __restrict__ x, const float* __restrict__ embed,
    const float* __restrict__ embedT, const float4* __restrict__ partial,
    float* __restrict__ out) {
  const int lane = threadIdx.x & 63;
  const int row  = blockIdx.x * 4 + (threadIdx.x >> 6);  // one wave per row

  // merge the 8 per-chunk top-2s (exact top-2 of union); uniform across lanes
  float a1, a2;
  int ia1, ia2;
  {
    const float4 p0 = partial[row];
    a1 = p0.x; ia1 = __float_as_int(p0.y);
    a2 = p0.z; ia2 = __float_as_int(p0.w);
    #pragma unroll
    for (int cc = 1; cc < NCHUNK; ++cc) {
      const float4 q = partial[(size_t)cc * NROWS + row];
      merge_top2(a1, ia1, a2, ia2, q.x, __float_as_int(q.y), q.z, __float_as_int(q.w));
    }
  }
  const int k1 = ia1;
  const int k2 = ia2;

  const float4 xv = *(const float4*)(x + (size_t)row * DIM + lane * 4);
  float4 e1v, e2v;
  if (USE_T) {
    e1v = *(const float4*)(embedT + (size_t)k1 * DIM + lane * 4);
    e2v = *(const float4*)(embedT + (size_t)k2 * DIM + lane * 4);
  } else {
    const int d = lane * 4;
    e1v.x = embed[(size_t)(d + 0) * NEMB + k1]; e1v.y = embed[(size_t)(d + 1) * NEMB + k1];
    e1v.z = embed[(size_t)(d + 2) * NEMB + k1]; e1v.w = embed[(size_t)(d + 3) * NEMB + k1];
    e2v.x = embed[(size_t)(d + 0) * NEMB + k2]; e2v.y = embed[(size_t)(d + 1) * NEMB + k2];
    e2v.z = embed[(size_t)(d + 2) * NEMB + k2]; e2v.w = embed[(size_t)(d + 3) * NEMB + k2];
  }

  double dot1 = (double)xv.x * e1v.x + (double)xv.y * e1v.y +
                (double)xv.z * e1v.z + (double)xv.w * e1v.w;
  double dot2 = (double)xv.x * e2v.x + (double)xv.y * e2v.y +
                (double)xv.z * e2v.z + (double)xv.w * e2v.w;
  double q1 = (double)e1v.x * e1v.x + (double)e1v.y * e1v.y +
              (double)e1v.z * e1v.z + (double)e1v.w * e1v.w;
  double q2 = (double)e2v.x * e2v.x + (double)e2v.y * e2v.y +
              (double)e2v.z * e2v.z + (double)e2v.w * e2v.w;

  #pragma unroll
  for (int m = 1; m < 64; m <<= 1) {
    dot1 += __shfl_xor(dot1, m);
    dot2 += __shfl_xor(dot2, m);
    q1   += __shfl_xor(q1, m);
    q2   += __shfl_xor(q2, m);
  }

  const double dist1 = q1 - 2.0 * dot1;
  const double dist2 = q2 - 2.0 * dot2;
  const bool pick1 = (dist1 < dist2) || (dist1 == dist2 && k1 <= k2);
  *(float4*)(out + (size_t)row * DIM + lane * 4) = pick1 ? e1v : e2v;
}

// ---------- round-1 fp32 argmin (fallback if ws too small) ----------
__global__ __launch_bounds__(256) void argmin_kernel(
    const float* __restrict__ x, const float* __restrict__ embed,
    const float* __restrict__ e_sq, int* __restrict__ out_i1, int* __restrict__ out_i2) {
  __shared__ float xsh[TM][DIM];
  __shared__ float rv1[4][TM], rv2[4][TM];
  __shared__ int   rj1[4][TM], rj2[4][TM];

  const int tid  = threadIdx.x;
  const int row0 = blockIdx.x * TM;
  {
    const float4* src = (const float4*)(x + (size_t)row0 * DIM);
    float4* dst = (float4*)xsh;
    #pragma unroll
    for (int i = 0; i < (TM * DIM / 4) / 256; ++i)
      dst[tid + 256 * i] = src[tid + 256 * i];
  }
  __syncthreads();

  float v1[TM], v2[TM];
  int   j1[TM], j2[TM];
  #pragma unroll
  for (int r = 0; r < TM; ++r) {
    v1[r] = __builtin_inff(); v2[r] = __builtin_inff();
    j1[r] = 0x7fffffff;       j2[r] = 0x7fffffff;
  }

  for (int c = 0; c < NEMB / (256 * TK); ++c) {
    const int k = c * (256 * TK) + tid * TK;
    float4 acc[TM];
    #pragma unroll
    for (int r = 0; r < TM; ++r) acc[r] = make_float4(0.f, 0.f, 0.f, 0.f);
    const float* eb = embed + k;
    #pragma unroll 2
    for (int d4 = 0; d4 < DIM / 4; ++d4) {
      const int d = d4 * 4;
      const float4 e0 = *(const float4*)(eb + (size_t)(d + 0) * NEMB);
      const float4 e1 = *(const float4*)(eb + (size_t)(d + 1) * NEMB);
      const float4 e2 = *(const float4*)(eb + (size_t)(d + 2) * NEMB);
      const float4 e3 = *(const float4*)(eb + (size_t)(d + 3) * NEMB);
      #pragma unroll
      for (int r = 0; r < TM; ++r) {
        const float4 xv = *(const float4*)&xsh[r][d];
        fma4(acc[r], xv.x, e0); fma4(acc[r], xv.y, e1);
        fma4(acc[r], xv.z, e2); fma4(acc[r], xv.w, e3);
      }
    }
    const float4 es = *(const float4*)(e_sq + k);
    #pragma unroll
    for (int r = 0; r < TM; ++r) {
      top2_bl(v1[r], j1[r], v2[r], j2[r], es.x - 2.f * acc[r].x, k + 0);
      top2_bl(v1[r], j1[r], v2[r], j2[r], es.y - 2.f * acc[r].y, k + 1);
      top2_bl(v1[r], j1[r], v2[r], j2[r], es.z - 2.f * acc[r].z, k + 2);
      top2_bl(v1[r], j1[r], v2[r], j2[r], es.w - 2.f * acc[r].w, k + 3);
    }
  }

  const int lane = tid & 63;
  const int wv   = tid >> 6;
  #pragma unroll
  for (int r = 0; r < TM; ++r) {
    float a1 = v1[r], a2 = v2[r];
    int ia1 = j1[r], ia2 = j2[r];
    #pragma unroll
    for (int m = 1; m < 64; m <<= 1) {
      const float b1 = __shfl_xor(a1, m);
      const int  ib1 = __shfl_xor(ia1, m);
      const float b2 = __shfl_xor(a2, m);
      const int  ib2 = __shfl_xor(ia2, m);
      merge_top2(a1, ia1, a2, ia2, b1, ib1, b2, ib2);
    }
    if (lane == 0) { rv1[wv][r] = a1; rv2[wv][r] = a2; rj1[wv][r] = ia1; rj2[wv][r] = ia2; }
  }
  __syncthreads();

  if (tid < TM) {
    float a1 = rv1[0][tid], a2 = rv2[0][tid];
    int ia1 = rj1[0][tid], ia2 = rj2[0][tid];
    #pragma unroll
    for (int w2 = 1; w2 < 4; ++w2)
      merge_top2(a1, ia1, a2, ia2, rv1[w2][tid], rj1[w2][tid], rv2[w2][tid], rj2[w2][tid]);
    out_i1[row0 + tid] = ia1;
    out_i2[row0 + tid] = ia2;
  }
}

// ---------- old refine (index-pair input, fallback path) ----------
__global__ __launch_bounds__(256) void refine_gather_kernel(
    const float* __restrict__ x, const float* __restrict__ embed,
    const int* __restrict__ in_i1, const int* __restrict__ in_i2,
    float* __restrict__ out) {
  const int lane = threadIdx.x & 63;
  const int row  = blockIdx.x * 4 + (threadIdx.x >> 6);
  const int k1 = in_i1[row];
  const int k2 = in_i2[row];

  const float4 xv = *(const float4*)(x + (size_t)row * DIM + lane * 4);
  float4 e1v, e2v;
  {
    const int d = lane * 4;
    e1v.x = embed[(size_t)(d + 0) * NEMB + k1]; e1v.y = embed[(size_t)(d + 1) * NEMB + k1];
    e1v.z = embed[(size_t)(d + 2) * NEMB + k1]; e1v.w = embed[(size_t)(d + 3) * NEMB + k1];
    e2v.x = embed[(size_t)(d + 0) * NEMB + k2]; e2v.y = embed[(size_t)(d + 1) * NEMB + k2];
    e2v.z = embed[(size_t)(d + 2) * NEMB + k2]; e2v.w = embed[(size_t)(d + 3) * NEMB + k2];
  }

  double dot1 = (double)xv.x * e1v.x + (double)xv.y * e1v.y +
                (double)xv.z * e1v.z + (double)xv.w * e1v.w;
  double dot2 = (double)xv.x * e2v.x + (double)xv.y * e2v.y +
                (double)xv.z * e2v.z + (double)xv.w * e2v.w;
  double q1 = (double)e1v.x * e1v.x + (double)e1v.y * e1v.y +
              (double)e1v.z * e1v.z + (double)e1v.w * e1v.w;
  double q2 = (double)e2v.x * e2v.x + (double)e2v.y * e2v.y +
              (double)e2v.z * e2v.z + (double)e2v.w * e2v.w;

  #pragma unroll
  for (int m = 1; m < 64; m <<= 1) {
    dot1 += __shfl_xor(dot1, m);
    dot2 += __shfl_xor(dot2, m);
    q1   += __shfl_xor(q1, m);
    q2   += __shfl_xor(q2, m);
  }

  const double dist1 = q1 - 2.0 * dot1;
  const double dist2 = q2 - 2.0 * dot2;
  const bool pick1 = (dist1 < dist2) || (dist1 == dist2 && k1 <= k2);
  *(float4*)(out + (size_t)row * DIM + lane * 4) = pick1 ? e1v : e2v;
}

// ---------- launch ----------
extern "C" void kernel_launch(void* const* d_in, const int* in_sizes, int n_in,
                              void* d_out, int out_size, void* d_ws, size_t ws_size,
                              hipStream_t stream) {
  const float* x     = (const float*)d_in[0];
  const float* embed = (const float*)d_in[1];
  float* out = (float*)d_out;

  char* ws = (char*)d_ws;
  const size_t embT_bytes  = (size_t)NEMB * DIM * sizeof(float);          // 8 MB
  const size_t epack_bytes = (size_t)NEMB * DIM * 2 * sizeof(short);      // 8 MB (hi+lo)
  const size_t esq_bytes   = (size_t)NEMB * sizeof(float);                // 32 KB
  const size_t part_bytes  = (size_t)NCHUNK * NROWS * sizeof(float4);     // 4 MB

  const bool tierA = ws_size >= embT_bytes + epack_bytes + esq_bytes + part_bytes;
  const bool tierB = ws_size >= epack_bytes + esq_bytes + part_bytes;

  if (tierA) {
    float*  embedT  = (float*)ws;
    uint4*  epack   = (uint4*)(ws + embT_bytes);
    float*  e_sq    = (float*)(ws + embT_bytes + epack_bytes);
    float4* partial = (float4*)(ws + embT_bytes + epack_bytes + esq_bytes);

    transpose_kernel<<<dim3(NEMB / 64, DIM / 64), 256, 0, stream>>>(embed, embedT);
    esq_kernel<<<NEMB / 256, 256, 0, stream>>>(embed, e_sq);
    pack_e_kernel<<<(NEMB / 16) * 8 * 64 / 256, 256, 0, stream>>>(embed, epack);
    argmin_mfma_kernel<<<(NROWS / 64) * NCHUNK, 256, 0, stream>>>(x, epack, e_sq, partial);
    merge_refine_kernel<true><<<NROWS / 4, 256, 0, stream>>>(x, embed, embedT, partial, out);
  } else if (tierB) {
    uint4*  epack   = (uint4*)ws;
    float*  e_sq    = (float*)(ws + epack_bytes);
    float4* partial = (float4*)(ws + epack_bytes + esq_bytes);

    esq_kernel<<<NEMB / 256, 256, 0, stream>>>(embed, e_sq);
    pack_e_kernel<<<(NEMB / 16) * 8 * 64 / 256, 256, 0, stream>>>(embed, epack);
    argmin_mfma_kernel<<<(NROWS / 64) * NCHUNK, 256, 0, stream>>>(x, epack, e_sq, partial);
    merge_refine_kernel<false><<<NROWS / 4, 256, 0, stream>>>(x, embed, nullptr, partial, out);
  } else {
    float* e_sq = (float*)ws;
    int*   i1   = (int*)(ws + esq_bytes);
    int*   i2   = i1 + NROWS;
    esq_kernel<<<NEMB / 256, 256, 0, stream>>>(embed, e_sq);
    argmin_kernel<<<NROWS / TM, 256, 0, stream>>>(x, embed, e_sq, i1, i2);
    refine_gather_kernel<<<NROWS / 4, 256, 0, stream>>>(x, embed, i1, i2, out);
  }
}

// Round 6
// 919.529 us; speedup vs baseline: 2.8025x; 1.1348x over previous
//
#include <hip/hip_runtime.h>
#include <cstddef>

#define DIM   256
#define NEMB  8192
#define NROWS 32768
#define NCHUNK 8              // code chunks, XCD-aligned via blockIdx&7
#define TM    16
#define TK    4

typedef __attribute__((ext_vector_type(8))) short short8;
typedef __attribute__((ext_vector_type(4))) float f32x4;

// ---------- helpers ----------
__device__ __forceinline__ bool better(float va, int ia, float vb, int ib) {
  return (va < vb) || (va == vb && ia < ib);
}

// branchless top-2 (strict <; per-lane scan order has increasing k, so ties keep first)
__device__ __forceinline__ void top2_bl(float& v1, int& i1, float& v2, int& i2,
                                        float d, int k) {
  const bool b1 = d < v1;
  const bool b2 = d < v2;
  const float nv2 = b1 ? v1 : (b2 ? d : v2);
  const int   ni2 = b1 ? i1 : (b2 ? k : i2);
  v1 = b1 ? d : v1;
  i1 = b1 ? k : i1;
  v2 = nv2;
  i2 = ni2;
}

__device__ __forceinline__ void merge_top2(float& a1, int& ia1, float& a2, int& ia2,
                                           float b1, int ib1, float b2, int ib2) {
  if (better(b1, ib1, a1, ia1)) {
    if (better(b2, ib2, a1, ia1)) { a1 = b1; ia1 = ib1; a2 = b2; ia2 = ib2; }
    else                          { a2 = a1; ia2 = ia1; a1 = b1; ia1 = ib1; }
  } else {
    if (better(b1, ib1, a2, ia2)) { a2 = b1; ia2 = ib1; }
  }
}

__device__ __forceinline__ void fma4(float4& a, float s, const float4& b) {
  a.x += s * b.x; a.y += s * b.y; a.z += s * b.z; a.w += s * b.w;
}

__device__ __forceinline__ unsigned short f2bf_rne(float f) {
  unsigned int u = __float_as_uint(f);
  u += 0x7FFFu + ((u >> 16) & 1u);
  return (unsigned short)(u >> 16);
}
__device__ __forceinline__ float bf2f(unsigned short h) {
  return __uint_as_float(((unsigned int)h) << 16);
}

// ---------- transpose: embedT[k*DIM + d] = embed[d*NEMB + k] ----------
__global__ __launch_bounds__(256) void transpose_kernel(const float* __restrict__ embed,
                                                        float* __restrict__ embedT) {
  __shared__ float tile[64][65];
  const int tx = threadIdx.x & 63;
  const int ty = threadIdx.x >> 6;
  const int k0 = blockIdx.x * 64;
  const int d0 = blockIdx.y * 64;
  #pragma unroll
  for (int i = 0; i < 16; ++i) {
    const int dl = ty + i * 4;
    tile[dl][tx] = embed[(size_t)(d0 + dl) * NEMB + k0 + tx];
  }
  __syncthreads();
  #pragma unroll
  for (int i = 0; i < 16; ++i) {
    const int kl = ty + i * 4;
    embedT[(size_t)(k0 + kl) * DIM + d0 + tx] = tile[tx][kl];
  }
}

// ---------- e_sq[k] = sum_d embed[d][k]^2 ----------
__global__ __launch_bounds__(256) void esq_kernel(const float* __restrict__ embed,
                                                  float* __restrict__ e_sq) {
  const int k = blockIdx.x * 256 + threadIdx.x;
  float s = 0.f;
  #pragma unroll 4
  for (int d = 0; d < DIM; ++d) {
    const float v = embed[(size_t)d * NEMB + k];
    s += v * v;
  }
  e_sq[k] = s;
}

// ---------- pack (-2*embed) into MFMA fragment layout, bf16 hi/lo ----------
// chunk index = ((ct*8 + ks)*2 + p)*64 + l  (uint4 = 8 bf16)
// lane l holds element (code = ct*16 + (l&15), dim = ks*32 + (l>>4)*8 + j).
// Used as the A operand (codes = M); layout is index-identical to B usage.
__global__ __launch_bounds__(256) void pack_e_kernel(const float* __restrict__ embed,
                                                     uint4* __restrict__ epack) {
  const int t  = blockIdx.x * 256 + threadIdx.x;
  const int l  = t & 63;
  const int ks = (t >> 6) & 7;
  const int ct = t >> 9;
  const int n     = ct * 16 + (l & 15);
  const int kbase = ks * 32 + (l >> 4) * 8;
  unsigned int h[4], lo[4];
  #pragma unroll
  for (int jj = 0; jj < 4; ++jj) {
    const float va = -2.f * embed[(size_t)(kbase + 2 * jj) * NEMB + n];
    const float vb = -2.f * embed[(size_t)(kbase + 2 * jj + 1) * NEMB + n];
    const unsigned short ha = f2bf_rne(va), hb = f2bf_rne(vb);
    const unsigned short la = f2bf_rne(va - bf2f(ha)), lb = f2bf_rne(vb - bf2f(hb));
    h[jj]  = (unsigned int)ha | ((unsigned int)hb << 16);
    lo[jj] = (unsigned int)la | ((unsigned int)lb << 16);
  }
  const size_t base = ((size_t)(ct * 8 + ks) * 2) * 64 + l;
  epack[base]      = make_uint4(h[0], h[1], h[2], h[3]);
  epack[base + 64] = make_uint4(lo[0], lo[1], lo[2], lo[3]);
}

// ---------- MFMA distance + per-row top-2 argmin, XCD-phased chunks ----------
// Swapped operands: codes = A (M dim), x-rows = B (N dim). C[m=code][n=row]:
// each lane sees 4 rows (n = lane&15) x (quad*4+r) codes -> top-2 state is
// only 16 regs/lane. 2 blocks/CU via __launch_bounds__(256,2).
// Explicit dbuf prefetch of epack A-frags across the ks loop.
__global__ __launch_bounds__(256, 2) void argmin_mfma_kernel(
    const float* __restrict__ x, const uint4* __restrict__ epack,
    const float* __restrict__ e_sq, float4* __restrict__ partial) {
  __shared__ uint4 xs[4 * 8 * 2 * 64];   // 64 KB: [rt][ks][p][lane] 16B chunks
  __shared__ float4 mbuf[4 * 64];        // 4 KB cross-wave merge

  const int tid  = threadIdx.x;
  const int lane = tid & 63;
  const int w    = tid >> 6;
  const int cc   = blockIdx.x & 7;
  const int row0 = (blockIdx.x >> 3) * 64;
  const int quad = lane >> 4;
  const int lcol = lane & 15;

  // ---- stage + split x into LDS, lane-dense ds_write_b64 order ----
  // g decode: h = g&1 (4-dim half), lp = (g>>1)&63, ks = (g>>7)&7, rt = g>>10
  #pragma unroll 4
  for (int i = 0; i < 16; ++i) {
    const int g   = tid + 256 * i;       // 0..4095
    const int h   = g & 1;
    const int lp  = (g >> 1) & 63;
    const int ks  = (g >> 7) & 7;
    const int rt  = g >> 10;
    const int row = rt * 16 + (lp & 15);
    const int f4  = ks * 8 + (lp >> 4) * 2 + h;
    const float4 v = ((const float4*)(x + (size_t)(row0 + row) * DIM))[f4];
    const unsigned short h0 = f2bf_rne(v.x), h1 = f2bf_rne(v.y),
                         h2 = f2bf_rne(v.z), h3 = f2bf_rne(v.w);
    const unsigned short l0 = f2bf_rne(v.x - bf2f(h0)), l1 = f2bf_rne(v.y - bf2f(h1)),
                         l2 = f2bf_rne(v.z - bf2f(h2)), l3 = f2bf_rne(v.w - bf2f(h3));
    unsigned short* bh = (unsigned short*)&xs[((rt * 8 + ks) * 2 + 0) * 64 + lp] + h * 4;
    unsigned short* bl = (unsigned short*)&xs[((rt * 8 + ks) * 2 + 1) * 64 + lp] + h * 4;
    *(uint2*)bh = make_uint2((unsigned int)h0 | ((unsigned int)h1 << 16),
                             (unsigned int)h2 | ((unsigned int)h3 << 16));
    *(uint2*)bl = make_uint2((unsigned int)l0 | ((unsigned int)l1 << 16),
                             (unsigned int)l2 | ((unsigned int)l3 << 16));
  }
  __syncthreads();

  // per-lane top-2 for 4 rows (one per rt): row = rt*16 + lcol
  float v1[4], v2[4];
  int   j1[4], j2[4];
  #pragma unroll
  for (int r = 0; r < 4; ++r) {
    v1[r] = __builtin_inff(); v2[r] = __builtin_inff();
    j1[r] = 0x7fffffff;       j2[r] = 0x7fffffff;
  }

  // chunk cc covers tiles [cc*64, (cc+1)*64); wave w takes cs*16 + w*4 + {0..3}
  for (int cs = 0; cs < 4; ++cs) {
    #pragma unroll
    for (int half = 0; half < 2; ++half) {
      const int ct0 = cc * 64 + cs * 16 + w * 4 + half * 2;   // 2 code tiles
      const float4 es0 = *(const float4*)(e_sq + (ct0 + 0) * 16 + quad * 4);
      const float4 es1 = *(const float4*)(e_sq + (ct0 + 1) * 16 + quad * 4);

      f32x4 acc[2][4];   // [c][rt]
      #pragma unroll
      for (int c = 0; c < 2; ++c)
        #pragma unroll
        for (int rt = 0; rt < 4; ++rt) acc[c][rt] = (f32x4){0.f, 0.f, 0.f, 0.f};

      const uint4* p0 = epack + (((size_t)(ct0 + 0) * 8) * 2) * 64 + lane;
      const uint4* p1 = epack + (((size_t)(ct0 + 1) * 8) * 2) * 64 + lane;

      short8 eh[2][2], el[2][2];   // dbuf [buf][c]
      eh[0][0] = *(const short8*)p0;  el[0][0] = *(const short8*)(p0 + 64);
      eh[0][1] = *(const short8*)p1;  el[0][1] = *(const short8*)(p1 + 64);

      #pragma unroll
      for (int ks = 0; ks < 8; ++ks) {
        const int cur = ks & 1, nxt = cur ^ 1;
        if (ks < 7) {   // prefetch next ks A-frags (+128 uint4 per ks step)
          const uint4* q0 = p0 + (size_t)(ks + 1) * 128;
          const uint4* q1 = p1 + (size_t)(ks + 1) * 128;
          eh[nxt][0] = *(const short8*)q0;  el[nxt][0] = *(const short8*)(q0 + 64);
          eh[nxt][1] = *(const short8*)q1;  el[nxt][1] = *(const short8*)(q1 + 64);
        }
        #pragma unroll
        for (int rt = 0; rt < 4; ++rt) {
          const short8 xh = *(const short8*)&xs[((rt * 8 + ks) * 2 + 0) * 64 + lane];
          const short8 xl = *(const short8*)&xs[((rt * 8 + ks) * 2 + 1) * 64 + lane];
          #pragma unroll
          for (int c = 0; c < 2; ++c) {
            acc[c][rt] = __builtin_amdgcn_mfma_f32_16x16x32_bf16(eh[cur][c], xh, acc[c][rt], 0, 0, 0);
            acc[c][rt] = __builtin_amdgcn_mfma_f32_16x16x32_bf16(el[cur][c], xh, acc[c][rt], 0, 0, 0);
            acc[c][rt] = __builtin_amdgcn_mfma_f32_16x16x32_bf16(eh[cur][c], xl, acc[c][rt], 0, 0, 0);
          }
        }
      }

      // acc = -2*dot ; dist = e_sq[code] + acc ; code = (ct0+c)*16 + quad*4 + r
      #pragma unroll
      for (int c = 0; c < 2; ++c) {
        const float4 es = (c == 0) ? es0 : es1;
        const int kb = (ct0 + c) * 16 + quad * 4;
        #pragma unroll
        for (int rt = 0; rt < 4; ++rt) {
          top2_bl(v1[rt], j1[rt], v2[rt], j2[rt], es.x + acc[c][rt][0], kb + 0);
          top2_bl(v1[rt], j1[rt], v2[rt], j2[rt], es.y + acc[c][rt][1], kb + 1);
          top2_bl(v1[rt], j1[rt], v2[rt], j2[rt], es.z + acc[c][rt][2], kb + 2);
          top2_bl(v1[rt], j1[rt], v2[rt], j2[rt], es.w + acc[c][rt][3], kb + 3);
        }
      }
    }
  }

  // ---- merge across the 4 quads (lanes sharing lcol -> same rows) ----
  #pragma unroll
  for (int rt = 0; rt < 4; ++rt) {
    float a1 = v1[rt], a2 = v2[rt];
    int ia1 = j1[rt], ia2 = j2[rt];
    #pragma unroll
    for (int m = 16; m < 64; m <<= 1) {
      const float b1 = __shfl_xor(a1, m);
      const int  ib1 = __shfl_xor(ia1, m);
      const float b2 = __shfl_xor(a2, m);
      const int  ib2 = __shfl_xor(ia2, m);
      merge_top2(a1, ia1, a2, ia2, b1, ib1, b2, ib2);
    }
    v1[rt] = a1; v2[rt] = a2; j1[rt] = ia1; j2[rt] = ia2;
  }
  if (quad == 0) {
    #pragma unroll
    for (int rt = 0; rt < 4; ++rt)
      mbuf[w * 64 + rt * 16 + lcol] = make_float4(v1[rt], __int_as_float(j1[rt]),
                                                  v2[rt], __int_as_float(j2[rt]));
  }
  __syncthreads();

  if (tid < 64) {
    float4 e0 = mbuf[tid];
    float a1 = e0.x, a2 = e0.z;
    int ia1 = __float_as_int(e0.y), ia2 = __float_as_int(e0.w);
    #pragma unroll
    for (int ww = 1; ww < 4; ++ww) {
      const float4 e = mbuf[ww * 64 + tid];
      merge_top2(a1, ia1, a2, ia2, e.x, __float_as_int(e.y), e.z, __float_as_int(e.w));
    }
    partial[(size_t)cc * NROWS + row0 + tid] =
        make_float4(a1, __int_as_float(ia1), a2, __int_as_float(ia2));
  }
}

// ---------- merge 8 chunk-partials + fp64 refine + gather ----------
template <bool USE_T>
__global__ __launch_bounds__(256) void merge_refine_kernel(
    const float* __restrict__ x, const float* __restrict__ embed,
    const float* __restrict__ embedT, const float4* __restrict__ partial,
    float* __restrict__ out) {
  const int lane = threadIdx.x & 63;
  const int row  = blockIdx.x * 4 + (threadIdx.x >> 6);  // one wave per row

  float a1, a2;
  int ia1, ia2;
  {
    const float4 p0 = partial[row];
    a1 = p0.x; ia1 = __float_as_int(p0.y);
    a2 = p0.z; ia2 = __float_as_int(p0.w);
    #pragma unroll
    for (int cc = 1; cc < NCHUNK; ++cc) {
      const float4 q = partial[(size_t)cc * NROWS + row];
      merge_top2(a1, ia1, a2, ia2, q.x, __float_as_int(q.y), q.z, __float_as_int(q.w));
    }
  }
  const int k1 = ia1;
  const int k2 = ia2;

  const float4 xv = *(const float4*)(x + (size_t)row * DIM + lane * 4);
  float4 e1v, e2v;
  if (USE_T) {
    e1v = *(const float4*)(embedT + (size_t)k1 * DIM + lane * 4);
    e2v = *(const float4*)(embedT + (size_t)k2 * DIM + lane * 4);
  } else {
    const int d = lane * 4;
    e1v.x = embed[(size_t)(d + 0) * NEMB + k1]; e1v.y = embed[(size_t)(d + 1) * NEMB + k1];
    e1v.z = embed[(size_t)(d + 2) * NEMB + k1]; e1v.w = embed[(size_t)(d + 3) * NEMB + k1];
    e2v.x = embed[(size_t)(d + 0) * NEMB + k2]; e2v.y = embed[(size_t)(d + 1) * NEMB + k2];
    e2v.z = embed[(size_t)(d + 2) * NEMB + k2]; e2v.w = embed[(size_t)(d + 3) * NEMB + k2];
  }

  double dot1 = (double)xv.x * e1v.x + (double)xv.y * e1v.y +
                (double)xv.z * e1v.z + (double)xv.w * e1v.w;
  double dot2 = (double)xv.x * e2v.x + (double)xv.y * e2v.y +
                (double)xv.z * e2v.z + (double)xv.w * e2v.w;
  double q1 = (double)e1v.x * e1v.x + (double)e1v.y * e1v.y +
              (double)e1v.z * e1v.z + (double)e1v.w * e1v.w;
  double q2 = (double)e2v.x * e2v.x + (double)e2v.y * e2v.y +
              (double)e2v.z * e2v.z + (double)e2v.w * e2v.w;

  #pragma unroll
  for (int m = 1; m < 64; m <<= 1) {
    dot1 += __shfl_xor(dot1, m);
    dot2 += __shfl_xor(dot2, m);
    q1   += __shfl_xor(q1, m);
    q2   += __shfl_xor(q2, m);
  }

  const double dist1 = q1 - 2.0 * dot1;
  const double dist2 = q2 - 2.0 * dot2;
  const bool pick1 = (dist1 < dist2) || (dist1 == dist2 && k1 <= k2);
  *(float4*)(out + (size_t)row * DIM + lane * 4) = pick1 ? e1v : e2v;
}

// ---------- round-1 fp32 argmin (fallback if ws too small) ----------
__global__ __launch_bounds__(256) void argmin_kernel(
    const float* __restrict__ x, const float* __restrict__ embed,
    const float* __restrict__ e_sq, int* __restrict__ out_i1, int* __restrict__ out_i2) {
  __shared__ float xsh[TM][DIM];
  __shared__ float rv1[4][TM], rv2[4][TM];
  __shared__ int   rj1[4][TM], rj2[4][TM];

  const int tid  = threadIdx.x;
  const int row0 = blockIdx.x * TM;
  {
    const float4* src = (const float4*)(x + (size_t)row0 * DIM);
    float4* dst = (float4*)xsh;
    #pragma unroll
    for (int i = 0; i < (TM * DIM / 4) / 256; ++i)
      dst[tid + 256 * i] = src[tid + 256 * i];
  }
  __syncthreads();

  float v1[TM], v2[TM];
  int   j1[TM], j2[TM];
  #pragma unroll
  for (int r = 0; r < TM; ++r) {
    v1[r] = __builtin_inff(); v2[r] = __builtin_inff();
    j1[r] = 0x7fffffff;       j2[r] = 0x7fffffff;
  }

  for (int c = 0; c < NEMB / (256 * TK); ++c) {
    const int k = c * (256 * TK) + tid * TK;
    float4 acc[TM];
    #pragma unroll
    for (int r = 0; r < TM; ++r) acc[r] = make_float4(0.f, 0.f, 0.f, 0.f);
    const float* eb = embed + k;
    #pragma unroll 2
    for (int d4 = 0; d4 < DIM / 4; ++d4) {
      const int d = d4 * 4;
      const float4 e0 = *(const float4*)(eb + (size_t)(d + 0) * NEMB);
      const float4 e1 = *(const float4*)(eb + (size_t)(d + 1) * NEMB);
      const float4 e2 = *(const float4*)(eb + (size_t)(d + 2) * NEMB);
      const float4 e3 = *(const float4*)(eb + (size_t)(d + 3) * NEMB);
      #pragma unroll
      for (int r = 0; r < TM; ++r) {
        const float4 xv = *(const float4*)&xsh[r][d];
        fma4(acc[r], xv.x, e0); fma4(acc[r], xv.y, e1);
        fma4(acc[r], xv.z, e2); fma4(acc[r], xv.w, e3);
      }
    }
    const float4 es = *(const float4*)(e_sq + k);
    #pragma unroll
    for (int r = 0; r < TM; ++r) {
      top2_bl(v1[r], j1[r], v2[r], j2[r], es.x - 2.f * acc[r].x, k + 0);
      top2_bl(v1[r], j1[r], v2[r], j2[r], es.y - 2.f * acc[r].y, k + 1);
      top2_bl(v1[r], j1[r], v2[r], j2[r], es.z - 2.f * acc[r].z, k + 2);
      top2_bl(v1[r], j1[r], v2[r], j2[r], es.w - 2.f * acc[r].w, k + 3);
    }
  }

  const int lane = tid & 63;
  const int wv   = tid >> 6;
  #pragma unroll
  for (int r = 0; r < TM; ++r) {
    float a1 = v1[r], a2 = v2[r];
    int ia1 = j1[r], ia2 = j2[r];
    #pragma unroll
    for (int m = 1; m < 64; m <<= 1) {
      const float b1 = __shfl_xor(a1, m);
      const int  ib1 = __shfl_xor(ia1, m);
      const float b2 = __shfl_xor(a2, m);
      const int  ib2 = __shfl_xor(ia2, m);
      merge_top2(a1, ia1, a2, ia2, b1, ib1, b2, ib2);
    }
    if (lane == 0) { rv1[wv][r] = a1; rv2[wv][r] = a2; rj1[wv][r] = ia1; rj2[wv][r] = ia2; }
  }
  __syncthreads();

  if (tid < TM) {
    float a1 = rv1[0][tid], a2 = rv2[0][tid];
    int ia1 = rj1[0][tid], ia2 = rj2[0][tid];
    #pragma unroll
    for (int w2 = 1; w2 < 4; ++w2)
      merge_top2(a1, ia1, a2, ia2, rv1[w2][tid], rj1[w2][tid], rv2[w2][tid], rj2[w2][tid]);
    out_i1[row0 + tid] = ia1;
    out_i2[row0 + tid] = ia2;
  }
}

// ---------- old refine (index-pair input, fallback path) ----------
__global__ __launch_bounds__(256) void refine_gather_kernel(
    const float* __restrict__ x, const float* __restrict__ embed,
    const int* __restrict__ in_i1, const int* __restrict__ in_i2,
    float* __restrict__ out) {
  const int lane = threadIdx.x & 63;
  const int row  = blockIdx.x * 4 + (threadIdx.x >> 6);
  const int k1 = in_i1[row];
  const int k2 = in_i2[row];

  const float4 xv = *(const float4*)(x + (size_t)row * DIM + lane * 4);
  float4 e1v, e2v;
  {
    const int d = lane * 4;
    e1v.x = embed[(size_t)(d + 0) * NEMB + k1]; e1v.y = embed[(size_t)(d + 1) * NEMB + k1];
    e1v.z = embed[(size_t)(d + 2) * NEMB + k1]; e1v.w = embed[(size_t)(d + 3) * NEMB + k1];
    e2v.x = embed[(size_t)(d + 0) * NEMB + k2]; e2v.y = embed[(size_t)(d + 1) * NEMB + k2];
    e2v.z = embed[(size_t)(d + 2) * NEMB + k2]; e2v.w = embed[(size_t)(d + 3) * NEMB + k2];
  }

  double dot1 = (double)xv.x * e1v.x + (double)xv.y * e1v.y +
                (double)xv.z * e1v.z + (double)xv.w * e1v.w;
  double dot2 = (double)xv.x * e2v.x + (double)xv.y * e2v.y +
                (double)xv.z * e2v.z + (double)xv.w * e2v.w;
  double q1 = (double)e1v.x * e1v.x + (double)e1v.y * e1v.y +
              (double)e1v.z * e1v.z + (double)e1v.w * e1v.w;
  double q2 = (double)e2v.x * e2v.x + (double)e2v.y * e2v.y +
              (double)e2v.z * e2v.z + (double)e2v.w * e2v.w;

  #pragma unroll
  for (int m = 1; m < 64; m <<= 1) {
    dot1 += __shfl_xor(dot1, m);
    dot2 += __shfl_xor(dot2, m);
    q1   += __shfl_xor(q1, m);
    q2   += __shfl_xor(q2, m);
  }

  const double dist1 = q1 - 2.0 * dot1;
  const double dist2 = q2 - 2.0 * dot2;
  const bool pick1 = (dist1 < dist2) || (dist1 == dist2 && k1 <= k2);
  *(float4*)(out + (size_t)row * DIM + lane * 4) = pick1 ? e1v : e2v;
}

// ---------- launch ----------
extern "C" void kernel_launch(void* const* d_in, const int* in_sizes, int n_in,
                              void* d_out, int out_size, void* d_ws, size_t ws_size,
                              hipStream_t stream) {
  const float* x     = (const float*)d_in[0];
  const float* embed = (const float*)d_in[1];
  float* out = (float*)d_out;

  char* ws = (char*)d_ws;
  const size_t embT_bytes  = (size_t)NEMB * DIM * sizeof(float);          // 8 MB
  const size_t epack_bytes = (size_t)NEMB * DIM * 2 * sizeof(short);      // 8 MB (hi+lo)
  const size_t esq_bytes   = (size_t)NEMB * sizeof(float);                // 32 KB
  const size_t part_bytes  = (size_t)NCHUNK * NROWS * sizeof(float4);     // 4 MB

  const bool tierA = ws_size >= embT_bytes + epack_bytes + esq_bytes + part_bytes;
  const bool tierB = ws_size >= epack_bytes + esq_bytes + part_bytes;

  if (tierA) {
    float*  embedT  = (float*)ws;
    uint4*  epack   = (uint4*)(ws + embT_bytes);
    float*  e_sq    = (float*)(ws + embT_bytes + epack_bytes);
    float4* partial = (float4*)(ws + embT_bytes + epack_bytes + esq_bytes);

    transpose_kernel<<<dim3(NEMB / 64, DIM / 64), 256, 0, stream>>>(embed, embedT);
    esq_kernel<<<NEMB / 256, 256, 0, stream>>>(embed, e_sq);
    pack_e_kernel<<<(NEMB / 16) * 8 * 64 / 256, 256, 0, stream>>>(embed, epack);
    argmin_mfma_kernel<<<(NROWS / 64) * NCHUNK, 256, 0, stream>>>(x, epack, e_sq, partial);
    merge_refine_kernel<true><<<NROWS / 4, 256, 0, stream>>>(x, embed, embedT, partial, out);
  } else if (tierB) {
    uint4*  epack   = (uint4*)ws;
    float*  e_sq    = (float*)(ws + epack_bytes);
    float4* partial = (float4*)(ws + epack_bytes + esq_bytes);

    esq_kernel<<<NEMB / 256, 256, 0, stream>>>(embed, e_sq);
    pack_e_kernel<<<(NEMB / 16) * 8 * 64 / 256, 256, 0, stream>>>(embed, epack);
    argmin_mfma_kernel<<<(NROWS / 64) * NCHUNK, 256, 0, stream>>>(x, epack, e_sq, partial);
    merge_refine_kernel<false><<<NROWS / 4, 256, 0, stream>>>(x, embed, nullptr, partial, out);
  } else {
    float* e_sq = (float*)ws;
    int*   i1   = (int*)(ws + esq_bytes);
    int*   i2   = i1 + NROWS;
    esq_kernel<<<NEMB / 256, 256, 0, stream>>>(embed, e_sq);
    argmin_kernel<<<NROWS / TM, 256, 0, stream>>>(x, embed, e_sq, i1, i2);
    refine_gather_kernel<<<NROWS / 4, 256, 0, stream>>>(x, embed, i1, i2, out);
  }
}

// Round 8
// 846.231 us; speedup vs baseline: 3.0453x; 1.0866x over previous
//
#include <hip/hip_runtime.h>
#include <cstddef>

#define DIM   256
#define NEMB  8192
#define NROWS 32768
#define NCHUNK 8              // code chunks, XCD-aligned via blockIdx&7
#define TM    16
#define TK    4

typedef __attribute__((ext_vector_type(8))) short short8;
typedef __attribute__((ext_vector_type(4))) float f32x4;

// ---------- helpers ----------
__device__ __forceinline__ bool better(float va, int ia, float vb, int ib) {
  return (va < vb) || (va == vb && ia < ib);
}

// branchless top-2 (strict <; per-lane scan order has increasing k, so ties keep first)
__device__ __forceinline__ void top2_bl(float& v1, int& i1, float& v2, int& i2,
                                        float d, int k) {
  const bool b1 = d < v1;
  const bool b2 = d < v2;
  const float nv2 = b1 ? v1 : (b2 ? d : v2);
  const int   ni2 = b1 ? i1 : (b2 ? k : i2);
  v1 = b1 ? d : v1;
  i1 = b1 ? k : i1;
  v2 = nv2;
  i2 = ni2;
}

__device__ __forceinline__ void merge_top2(float& a1, int& ia1, float& a2, int& ia2,
                                           float b1, int ib1, float b2, int ib2) {
  if (better(b1, ib1, a1, ia1)) {
    if (better(b2, ib2, a1, ia1)) { a1 = b1; ia1 = ib1; a2 = b2; ia2 = ib2; }
    else                          { a2 = a1; ia2 = ia1; a1 = b1; ia1 = ib1; }
  } else {
    if (better(b1, ib1, a2, ia2)) { a2 = b1; ia2 = ib1; }
  }
}

__device__ __forceinline__ void fma4(float4& a, float s, const float4& b) {
  a.x += s * b.x; a.y += s * b.y; a.z += s * b.z; a.w += s * b.w;
}

__device__ __forceinline__ unsigned short f2bf_rne(float f) {
  unsigned int u = __float_as_uint(f);
  u += 0x7FFFu + ((u >> 16) & 1u);
  return (unsigned short)(u >> 16);
}
__device__ __forceinline__ float bf2f(unsigned short h) {
  return __uint_as_float(((unsigned int)h) << 16);
}

// ---------- transpose: embedT[k*DIM + d] = embed[d*NEMB + k] ----------
__global__ __launch_bounds__(256) void transpose_kernel(const float* __restrict__ embed,
                                                        float* __restrict__ embedT) {
  __shared__ float tile[64][65];
  const int tx = threadIdx.x & 63;
  const int ty = threadIdx.x >> 6;
  const int k0 = blockIdx.x * 64;
  const int d0 = blockIdx.y * 64;
  #pragma unroll
  for (int i = 0; i < 16; ++i) {
    const int dl = ty + i * 4;
    tile[dl][tx] = embed[(size_t)(d0 + dl) * NEMB + k0 + tx];
  }
  __syncthreads();
  #pragma unroll
  for (int i = 0; i < 16; ++i) {
    const int kl = ty + i * 4;
    embedT[(size_t)(k0 + kl) * DIM + d0 + tx] = tile[tx][kl];
  }
}

// ---------- e_sq[k] = sum_d embed[d][k]^2 ----------
__global__ __launch_bounds__(256) void esq_kernel(const float* __restrict__ embed,
                                                  float* __restrict__ e_sq) {
  const int k = blockIdx.x * 256 + threadIdx.x;
  float s = 0.f;
  #pragma unroll 4
  for (int d = 0; d < DIM; ++d) {
    const float v = embed[(size_t)d * NEMB + k];
    s += v * v;
  }
  e_sq[k] = s;
}

// ---------- pack (-2*embed) into MFMA fragment layout, bf16 hi/lo ----------
// chunk index = ((ct*8 + ks)*2 + p)*64 + l  (uint4 = 8 bf16)
// lane l holds element (code = ct*16 + (l&15), dim = ks*32 + (l>>4)*8 + j).
// Used as the A operand (codes = M).
__global__ __launch_bounds__(256) void pack_e_kernel(const float* __restrict__ embed,
                                                     uint4* __restrict__ epack) {
  const int t  = blockIdx.x * 256 + threadIdx.x;
  const int l  = t & 63;
  const int ks = (t >> 6) & 7;
  const int ct = t >> 9;
  const int n     = ct * 16 + (l & 15);
  const int kbase = ks * 32 + (l >> 4) * 8;
  unsigned int h[4], lo[4];
  #pragma unroll
  for (int jj = 0; jj < 4; ++jj) {
    const float va = -2.f * embed[(size_t)(kbase + 2 * jj) * NEMB + n];
    const float vb = -2.f * embed[(size_t)(kbase + 2 * jj + 1) * NEMB + n];
    const unsigned short ha = f2bf_rne(va), hb = f2bf_rne(vb);
    const unsigned short la = f2bf_rne(va - bf2f(ha)), lb = f2bf_rne(vb - bf2f(hb));
    h[jj]  = (unsigned int)ha | ((unsigned int)hb << 16);
    lo[jj] = (unsigned int)la | ((unsigned int)lb << 16);
  }
  const size_t base = ((size_t)(ct * 8 + ks) * 2) * 64 + l;
  epack[base]      = make_uint4(h[0], h[1], h[2], h[3]);
  epack[base + 64] = make_uint4(lo[0], lo[1], lo[2], lo[3]);
}

// ---------- MFMA distance + per-row top-2 argmin, XCD-phased chunks ----------
// codes = A (M dim), x-rows = B (N dim). C[m=code][n=row]: each lane's top-2
// covers 4 rows (16 regs). 4 code-tiles per pass: 48 MFMA per 8 ds_read_b128
// (LDS pipe ~40% of MFMA pipe). NO manual dbuf (round-6 spill lesson: at
// (256,2) arch-VGPR cap is 128; keep arch demand lean, acc in AGPRs).
__global__ __launch_bounds__(256, 2) void argmin_mfma_kernel(
    const float* __restrict__ x, const uint4* __restrict__ epack,
    const float* __restrict__ e_sq, float4* __restrict__ partial) {
  __shared__ uint4 xs[4 * 8 * 2 * 64];   // 64 KB: [rt][ks][p][lane] 16B chunks
  __shared__ float4 mbuf[4 * 64];        // 4 KB cross-wave merge

  const int tid  = threadIdx.x;
  const int lane = tid & 63;
  const int w    = tid >> 6;
  const int cc   = blockIdx.x & 7;
  const int row0 = (blockIdx.x >> 3) * 64;
  const int quad = lane >> 4;
  const int lcol = lane & 15;

  // ---- stage + split x into LDS, lane-dense ds_write_b64 order ----
  // g decode: h = g&1 (4-dim half), lp = (g>>1)&63, ks = (g>>7)&7, rt = g>>10
  #pragma unroll 4
  for (int i = 0; i < 16; ++i) {
    const int g   = tid + 256 * i;       // 0..4095
    const int h   = g & 1;
    const int lp  = (g >> 1) & 63;
    const int ks  = (g >> 7) & 7;
    const int rt  = g >> 10;
    const int row = rt * 16 + (lp & 15);
    const int f4  = ks * 8 + (lp >> 4) * 2 + h;
    const float4 v = ((const float4*)(x + (size_t)(row0 + row) * DIM))[f4];
    const unsigned short h0 = f2bf_rne(v.x), h1 = f2bf_rne(v.y),
                         h2 = f2bf_rne(v.z), h3 = f2bf_rne(v.w);
    const unsigned short l0 = f2bf_rne(v.x - bf2f(h0)), l1 = f2bf_rne(v.y - bf2f(h1)),
                         l2 = f2bf_rne(v.z - bf2f(h2)), l3 = f2bf_rne(v.w - bf2f(h3));
    unsigned short* bh = (unsigned short*)&xs[((rt * 8 + ks) * 2 + 0) * 64 + lp] + h * 4;
    unsigned short* bl = (unsigned short*)&xs[((rt * 8 + ks) * 2 + 1) * 64 + lp] + h * 4;
    *(uint2*)bh = make_uint2((unsigned int)h0 | ((unsigned int)h1 << 16),
                             (unsigned int)h2 | ((unsigned int)h3 << 16));
    *(uint2*)bl = make_uint2((unsigned int)l0 | ((unsigned int)l1 << 16),
                             (unsigned int)l2 | ((unsigned int)l3 << 16));
  }
  __syncthreads();

  // per-lane top-2 for 4 rows (one per rt): row = rt*16 + lcol
  float v1[4], v2[4];
  int   j1[4], j2[4];
  #pragma unroll
  for (int r = 0; r < 4; ++r) {
    v1[r] = __builtin_inff(); v2[r] = __builtin_inff();
    j1[r] = 0x7fffffff;       j2[r] = 0x7fffffff;
  }

  // chunk cc covers tiles [cc*64, (cc+1)*64); wave w takes cs*16 + w*4 + {0..3}
  for (int cs = 0; cs < 4; ++cs) {
    const int ct0 = cc * 64 + cs * 16 + w * 4;           // 4 code tiles
    const uint4* pb = epack + (size_t)ct0 * 1024 + lane; // tile stride 1024 uint4

    // e_sq for the 4 tiles (issued early, hidden behind MFMAs)
    float4 es[4];
    #pragma unroll
    for (int c = 0; c < 4; ++c)
      es[c] = *(const float4*)(e_sq + (ct0 + c) * 16 + quad * 4);

    f32x4 acc[4][4];   // [c][rt] -> AGPRs
    #pragma unroll
    for (int c = 0; c < 4; ++c)
      #pragma unroll
      for (int rt = 0; rt < 4; ++rt) acc[c][rt] = (f32x4){0.f, 0.f, 0.f, 0.f};

    #pragma unroll
    for (int ks = 0; ks < 8; ++ks) {
      short8 eh[4], el[4];
      #pragma unroll
      for (int c = 0; c < 4; ++c) {
        eh[c] = *(const short8*)(pb + c * 1024 + ks * 128);
        el[c] = *(const short8*)(pb + c * 1024 + ks * 128 + 64);
      }
      #pragma unroll
      for (int rt = 0; rt < 4; ++rt) {
        const short8 xh = *(const short8*)&xs[((rt * 8 + ks) * 2 + 0) * 64 + lane];
        const short8 xl = *(const short8*)&xs[((rt * 8 + ks) * 2 + 1) * 64 + lane];
        #pragma unroll
        for (int c = 0; c < 4; ++c) {
          acc[c][rt] = __builtin_amdgcn_mfma_f32_16x16x32_bf16(eh[c], xh, acc[c][rt], 0, 0, 0);
          acc[c][rt] = __builtin_amdgcn_mfma_f32_16x16x32_bf16(el[c], xh, acc[c][rt], 0, 0, 0);
          acc[c][rt] = __builtin_amdgcn_mfma_f32_16x16x32_bf16(eh[c], xl, acc[c][rt], 0, 0, 0);
        }
      }
    }

    // acc = -2*dot ; dist = e_sq[code] + acc ; code = (ct0+c)*16 + quad*4 + r
    #pragma unroll
    for (int c = 0; c < 4; ++c) {
      const int kb = (ct0 + c) * 16 + quad * 4;
      #pragma unroll
      for (int rt = 0; rt < 4; ++rt) {
        top2_bl(v1[rt], j1[rt], v2[rt], j2[rt], es[c].x + acc[c][rt][0], kb + 0);
        top2_bl(v1[rt], j1[rt], v2[rt], j2[rt], es[c].y + acc[c][rt][1], kb + 1);
        top2_bl(v1[rt], j1[rt], v2[rt], j2[rt], es[c].z + acc[c][rt][2], kb + 2);
        top2_bl(v1[rt], j1[rt], v2[rt], j2[rt], es[c].w + acc[c][rt][3], kb + 3);
      }
    }
  }

  // ---- merge across the 4 quads (lanes sharing lcol -> same rows) ----
  #pragma unroll
  for (int rt = 0; rt < 4; ++rt) {
    float a1 = v1[rt], a2 = v2[rt];
    int ia1 = j1[rt], ia2 = j2[rt];
    #pragma unroll
    for (int m = 16; m < 64; m <<= 1) {
      const float b1 = __shfl_xor(a1, m);
      const int  ib1 = __shfl_xor(ia1, m);
      const float b2 = __shfl_xor(a2, m);
      const int  ib2 = __shfl_xor(ia2, m);
      merge_top2(a1, ia1, a2, ia2, b1, ib1, b2, ib2);
    }
    v1[rt] = a1; v2[rt] = a2; j1[rt] = ia1; j2[rt] = ia2;
  }
  if (quad == 0) {
    #pragma unroll
    for (int rt = 0; rt < 4; ++rt)
      mbuf[w * 64 + rt * 16 + lcol] = make_float4(v1[rt], __int_as_float(j1[rt]),
                                                  v2[rt], __int_as_float(j2[rt]));
  }
  __syncthreads();

  if (tid < 64) {
    float4 e0 = mbuf[tid];
    float a1 = e0.x, a2 = e0.z;
    int ia1 = __float_as_int(e0.y), ia2 = __float_as_int(e0.w);
    #pragma unroll
    for (int ww = 1; ww < 4; ++ww) {
      const float4 e = mbuf[ww * 64 + tid];
      merge_top2(a1, ia1, a2, ia2, e.x, __float_as_int(e.y), e.z, __float_as_int(e.w));
    }
    partial[(size_t)cc * NROWS + row0 + tid] =
        make_float4(a1, __int_as_float(ia1), a2, __int_as_float(ia2));
  }
}

// ---------- merge 8 chunk-partials + fp64 refine + gather ----------
template <bool USE_T>
__global__ __launch_bounds__(256) void merge_refine_kernel(
    const float* __restrict__ x, const float* __restrict__ embed,
    const float* __restrict__ embedT, const float4* __restrict__ partial,
    float* __restrict__ out) {
  const int lane = threadIdx.x & 63;
  const int row  = blockIdx.x * 4 + (threadIdx.x >> 6);  // one wave per row

  float a1, a2;
  int ia1, ia2;
  {
    const float4 p0 = partial[row];
    a1 = p0.x; ia1 = __float_as_int(p0.y);
    a2 = p0.z; ia2 = __float_as_int(p0.w);
    #pragma unroll
    for (int cc = 1; cc < NCHUNK; ++cc) {
      const float4 q = partial[(size_t)cc * NROWS + row];
      merge_top2(a1, ia1, a2, ia2, q.x, __float_as_int(q.y), q.z, __float_as_int(q.w));
    }
  }
  const int k1 = ia1;
  const int k2 = ia2;

  const float4 xv = *(const float4*)(x + (size_t)row * DIM + lane * 4);
  float4 e1v, e2v;
  if (USE_T) {
    e1v = *(const float4*)(embedT + (size_t)k1 * DIM + lane * 4);
    e2v = *(const float4*)(embedT + (size_t)k2 * DIM + lane * 4);
  } else {
    const int d = lane * 4;
    e1v.x = embed[(size_t)(d + 0) * NEMB + k1]; e1v.y = embed[(size_t)(d + 1) * NEMB + k1];
    e1v.z = embed[(size_t)(d + 2) * NEMB + k1]; e1v.w = embed[(size_t)(d + 3) * NEMB + k1];
    e2v.x = embed[(size_t)(d + 0) * NEMB + k2]; e2v.y = embed[(size_t)(d + 1) * NEMB + k2];
    e2v.z = embed[(size_t)(d + 2) * NEMB + k2]; e2v.w = embed[(size_t)(d + 3) * NEMB + k2];
  }

  double dot1 = (double)xv.x * e1v.x + (double)xv.y * e1v.y +
                (double)xv.z * e1v.z + (double)xv.w * e1v.w;
  double dot2 = (double)xv.x * e2v.x + (double)xv.y * e2v.y +
                (double)xv.z * e2v.z + (double)xv.w * e2v.w;
  double q1 = (double)e1v.x * e1v.x + (double)e1v.y * e1v.y +
              (double)e1v.z * e1v.z + (double)e1v.w * e1v.w;
  double q2 = (double)e2v.x * e2v.x + (double)e2v.y * e2v.y +
              (double)e2v.z * e2v.z + (double)e2v.w * e2v.w;

  #pragma unroll
  for (int m = 1; m < 64; m <<= 1) {
    dot1 += __shfl_xor(dot1, m);
    dot2 += __shfl_xor(dot2, m);
    q1   += __shfl_xor(q1, m);
    q2   += __shfl_xor(q2, m);
  }

  const double dist1 = q1 - 2.0 * dot1;
  const double dist2 = q2 - 2.0 * dot2;
  const bool pick1 = (dist1 < dist2) || (dist1 == dist2 && k1 <= k2);
  *(float4*)(out + (size_t)row * DIM + lane * 4) = pick1 ? e1v : e2v;
}

// ---------- round-1 fp32 argmin (fallback if ws too small) ----------
__global__ __launch_bounds__(256) void argmin_kernel(
    const float* __restrict__ x, const float* __restrict__ embed,
    const float* __restrict__ e_sq, int* __restrict__ out_i1, int* __restrict__ out_i2) {
  __shared__ float xsh[TM][DIM];
  __shared__ float rv1[4][TM], rv2[4][TM];
  __shared__ int   rj1[4][TM], rj2[4][TM];

  const int tid  = threadIdx.x;
  const int row0 = blockIdx.x * TM;
  {
    const float4* src = (const float4*)(x + (size_t)row0 * DIM);
    float4* dst = (float4*)xsh;
    #pragma unroll
    for (int i = 0; i < (TM * DIM / 4) / 256; ++i)
      dst[tid + 256 * i] = src[tid + 256 * i];
  }
  __syncthreads();

  float v1[TM], v2[TM];
  int   j1[TM], j2[TM];
  #pragma unroll
  for (int r = 0; r < TM; ++r) {
    v1[r] = __builtin_inff(); v2[r] = __builtin_inff();
    j1[r] = 0x7fffffff;       j2[r] = 0x7fffffff;
  }

  for (int c = 0; c < NEMB / (256 * TK); ++c) {
    const int k = c * (256 * TK) + tid * TK;
    float4 acc[TM];
    #pragma unroll
    for (int r = 0; r < TM; ++r) acc[r] = make_float4(0.f, 0.f, 0.f, 0.f);
    const float* eb = embed + k;
    #pragma unroll 2
    for (int d4 = 0; d4 < DIM / 4; ++d4) {
      const int d = d4 * 4;
      const float4 e0 = *(const float4*)(eb + (size_t)(d + 0) * NEMB);
      const float4 e1 = *(const float4*)(eb + (size_t)(d + 1) * NEMB);
      const float4 e2 = *(const float4*)(eb + (size_t)(d + 2) * NEMB);
      const float4 e3 = *(const float4*)(eb + (size_t)(d + 3) * NEMB);
      #pragma unroll
      for (int r = 0; r < TM; ++r) {
        const float4 xv = *(const float4*)&xsh[r][d];
        fma4(acc[r], xv.x, e0); fma4(acc[r], xv.y, e1);
        fma4(acc[r], xv.z, e2); fma4(acc[r], xv.w, e3);
      }
    }
    const float4 es = *(const float4*)(e_sq + k);
    #pragma unroll
    for (int r = 0; r < TM; ++r) {
      top2_bl(v1[r], j1[r], v2[r], j2[r], es.x - 2.f * acc[r].x, k + 0);
      top2_bl(v1[r], j1[r], v2[r], j2[r], es.y - 2.f * acc[r].y, k + 1);
      top2_bl(v1[r], j1[r], v2[r], j2[r], es.z - 2.f * acc[r].z, k + 2);
      top2_bl(v1[r], j1[r], v2[r], j2[r], es.w - 2.f * acc[r].w, k + 3);
    }
  }

  const int lane = tid & 63;
  const int wv   = tid >> 6;
  #pragma unroll
  for (int r = 0; r < TM; ++r) {
    float a1 = v1[r], a2 = v2[r];
    int ia1 = j1[r], ia2 = j2[r];
    #pragma unroll
    for (int m = 1; m < 64; m <<= 1) {
      const float b1 = __shfl_xor(a1, m);
      const int  ib1 = __shfl_xor(ia1, m);
      const float b2 = __shfl_xor(a2, m);
      const int  ib2 = __shfl_xor(ia2, m);
      merge_top2(a1, ia1, a2, ia2, b1, ib1, b2, ib2);
    }
    if (lane == 0) { rv1[wv][r] = a1; rv2[wv][r] = a2; rj1[wv][r] = ia1; rj2[wv][r] = ia2; }
  }
  __syncthreads();

  if (tid < TM) {
    float a1 = rv1[0][tid], a2 = rv2[0][tid];
    int ia1 = rj1[0][tid], ia2 = rj2[0][tid];
    #pragma unroll
    for (int w2 = 1; w2 < 4; ++w2)
      merge_top2(a1, ia1, a2, ia2, rv1[w2][tid], rj1[w2][tid], rv2[w2][tid], rj2[w2][tid]);
    out_i1[row0 + tid] = ia1;
    out_i2[row0 + tid] = ia2;
  }
}

// ---------- old refine (index-pair input, fallback path) ----------
__global__ __launch_bounds__(256) void refine_gather_kernel(
    const float* __restrict__ x, const float* __restrict__ embed,
    const int* __restrict__ in_i1, const int* __restrict__ in_i2,
    float* __restrict__ out) {
  const int lane = threadIdx.x & 63;
  const int row  = blockIdx.x * 4 + (threadIdx.x >> 6);
  const int k1 = in_i1[row];
  const int k2 = in_i2[row];

  const float4 xv = *(const float4*)(x + (size_t)row * DIM + lane * 4);
  float4 e1v, e2v;
  {
    const int d = lane * 4;
    e1v.x = embed[(size_t)(d + 0) * NEMB + k1]; e1v.y = embed[(size_t)(d + 1) * NEMB + k1];
    e1v.z = embed[(size_t)(d + 2) * NEMB + k1]; e1v.w = embed[(size_t)(d + 3) * NEMB + k1];
    e2v.x = embed[(size_t)(d + 0) * NEMB + k2]; e2v.y = embed[(size_t)(d + 1) * NEMB + k2];
    e2v.z = embed[(size_t)(d + 2) * NEMB + k2]; e2v.w = embed[(size_t)(d + 3) * NEMB + k2];
  }

  double dot1 = (double)xv.x * e1v.x + (double)xv.y * e1v.y +
                (double)xv.z * e1v.z + (double)xv.w * e1v.w;
  double dot2 = (double)xv.x * e2v.x + (double)xv.y * e2v.y +
                (double)xv.z * e2v.z + (double)xv.w * e2v.w;
  double q1 = (double)e1v.x * e1v.x + (double)e1v.y * e1v.y +
              (double)e1v.z * e1v.z + (double)e1v.w * e1v.w;
  double q2 = (double)e2v.x * e2v.x + (double)e2v.y * e2v.y +
              (double)e2v.z * e2v.z + (double)e2v.w * e2v.w;

  #pragma unroll
  for (int m = 1; m < 64; m <<= 1) {
    dot1 += __shfl_xor(dot1, m);
    dot2 += __shfl_xor(dot2, m);
    q1   += __shfl_xor(q1, m);
    q2   += __shfl_xor(q2, m);
  }

  const double dist1 = q1 - 2.0 * dot1;
  const double dist2 = q2 - 2.0 * dot2;
  const bool pick1 = (dist1 < dist2) || (dist1 == dist2 && k1 <= k2);
  *(float4*)(out + (size_t)row * DIM + lane * 4) = pick1 ? e1v : e2v;
}

// ---------- launch ----------
extern "C" void kernel_launch(void* const* d_in, const int* in_sizes, int n_in,
                              void* d_out, int out_size, void* d_ws, size_t ws_size,
                              hipStream_t stream) {
  const float* x     = (const float*)d_in[0];
  const float* embed = (const float*)d_in[1];
  float* out = (float*)d_out;

  char* ws = (char*)d_ws;
  const size_t embT_bytes  = (size_t)NEMB * DIM * sizeof(float);          // 8 MB
  const size_t epack_bytes = (size_t)NEMB * DIM * 2 * sizeof(short);      // 8 MB (hi+lo)
  const size_t esq_bytes   = (size_t)NEMB * sizeof(float);                // 32 KB
  const size_t part_bytes  = (size_t)NCHUNK * NROWS * sizeof(float4);     // 4 MB

  const bool tierA = ws_size >= embT_bytes + epack_bytes + esq_bytes + part_bytes;
  const bool tierB = ws_size >= epack_bytes + esq_bytes + part_bytes;

  if (tierA) {
    float*  embedT  = (float*)ws;
    uint4*  epack   = (uint4*)(ws + embT_bytes);
    float*  e_sq    = (float*)(ws + embT_bytes + epack_bytes);
    float4* partial = (float4*)(ws + embT_bytes + epack_bytes + esq_bytes);

    transpose_kernel<<<dim3(NEMB / 64, DIM / 64), 256, 0, stream>>>(embed, embedT);
    esq_kernel<<<NEMB / 256, 256, 0, stream>>>(embed, e_sq);
    pack_e_kernel<<<(NEMB / 16) * 8 * 64 / 256, 256, 0, stream>>>(embed, epack);
    argmin_mfma_kernel<<<(NROWS / 64) * NCHUNK, 256, 0, stream>>>(x, epack, e_sq, partial);
    merge_refine_kernel<true><<<NROWS / 4, 256, 0, stream>>>(x, embed, embedT, partial, out);
  } else if (tierB) {
    uint4*  epack   = (uint4*)ws;
    float*  e_sq    = (float*)(ws + epack_bytes);
    float4* partial = (float4*)(ws + epack_bytes + esq_bytes);

    esq_kernel<<<NEMB / 256, 256, 0, stream>>>(embed, e_sq);
    pack_e_kernel<<<(NEMB / 16) * 8 * 64 / 256, 256, 0, stream>>>(embed, epack);
    argmin_mfma_kernel<<<(NROWS / 64) * NCHUNK, 256, 0, stream>>>(x, epack, e_sq, partial);
    merge_refine_kernel<false><<<NROWS / 4, 256, 0, stream>>>(x, embed, nullptr, partial, out);
  } else {
    float* e_sq = (float*)ws;
    int*   i1   = (int*)(ws + esq_bytes);
    int*   i2   = i1 + NROWS;
    esq_kernel<<<NEMB / 256, 256, 0, stream>>>(embed, e_sq);
    argmin_kernel<<<NROWS / TM, 256, 0, stream>>>(x, embed, e_sq, i1, i2);
    refine_gather_kernel<<<NROWS / 4, 256, 0, stream>>>(x, embed, i1, i2, out);
  }
}

// Round 9
// 533.306 us; speedup vs baseline: 4.8322x; 1.5868x over previous
//
#include <hip/hip_runtime.h>
#include <cstddef>

#define DIM   256
#define NEMB  8192
#define NROWS 32768
#define NCHUNK 8              // code chunks, XCD-aligned via blockIdx&7
#define TM    16
#define TK    4

typedef __attribute__((ext_vector_type(8))) short short8;
typedef __attribute__((ext_vector_type(4))) float f32x4;

// ---------- helpers ----------
__device__ __forceinline__ bool better(float va, int ia, float vb, int ib) {
  return (va < vb) || (va == vb && ia < ib);
}

// branchless top-2 (strict <; per-lane scan order has increasing k, so ties keep first)
__device__ __forceinline__ void top2_bl(float& v1, int& i1, float& v2, int& i2,
                                        float d, int k) {
  const bool b1 = d < v1;
  const bool b2 = d < v2;
  const float nv2 = b1 ? v1 : (b2 ? d : v2);
  const int   ni2 = b1 ? i1 : (b2 ? k : i2);
  v1 = b1 ? d : v1;
  i1 = b1 ? k : i1;
  v2 = nv2;
  i2 = ni2;
}

__device__ __forceinline__ void merge_top2(float& a1, int& ia1, float& a2, int& ia2,
                                           float b1, int ib1, float b2, int ib2) {
  if (better(b1, ib1, a1, ia1)) {
    if (better(b2, ib2, a1, ia1)) { a1 = b1; ia1 = ib1; a2 = b2; ia2 = ib2; }
    else                          { a2 = a1; ia2 = ia1; a1 = b1; ia1 = ib1; }
  } else {
    if (better(b1, ib1, a2, ia2)) { a2 = b1; ia2 = ib1; }
  }
}

__device__ __forceinline__ void fma4(float4& a, float s, const float4& b) {
  a.x += s * b.x; a.y += s * b.y; a.z += s * b.z; a.w += s * b.w;
}

__device__ __forceinline__ unsigned short f2bf_rne(float f) {
  unsigned int u = __float_as_uint(f);
  u += 0x7FFFu + ((u >> 16) & 1u);
  return (unsigned short)(u >> 16);
}
__device__ __forceinline__ float bf2f(unsigned short h) {
  return __uint_as_float(((unsigned int)h) << 16);
}

// ---------- transpose: embedT[k*DIM + d] = embed[d*NEMB + k] ----------
__global__ __launch_bounds__(256) void transpose_kernel(const float* __restrict__ embed,
                                                        float* __restrict__ embedT) {
  __shared__ float tile[64][65];
  const int tx = threadIdx.x & 63;
  const int ty = threadIdx.x >> 6;
  const int k0 = blockIdx.x * 64;
  const int d0 = blockIdx.y * 64;
  #pragma unroll
  for (int i = 0; i < 16; ++i) {
    const int dl = ty + i * 4;
    tile[dl][tx] = embed[(size_t)(d0 + dl) * NEMB + k0 + tx];
  }
  __syncthreads();
  #pragma unroll
  for (int i = 0; i < 16; ++i) {
    const int kl = ty + i * 4;
    embedT[(size_t)(k0 + kl) * DIM + d0 + tx] = tile[tx][kl];
  }
}

// ---------- e_sq[k] = sum_d embed[d][k]^2 ----------
__global__ __launch_bounds__(256) void esq_kernel(const float* __restrict__ embed,
                                                  float* __restrict__ e_sq) {
  const int k = blockIdx.x * 256 + threadIdx.x;
  float s = 0.f;
  #pragma unroll 4
  for (int d = 0; d < DIM; ++d) {
    const float v = embed[(size_t)d * NEMB + k];
    s += v * v;
  }
  e_sq[k] = s;
}

// ---------- pack (-2*embed) into MFMA fragment layout, bf16 hi/lo ----------
// chunk index = ((ct*8 + ks)*2 + p)*64 + l  (uint4 = 8 bf16)
// lane l holds element (code = ct*16 + (l&15), dim = ks*32 + (l>>4)*8 + j).
// Used as the A operand (codes = M).
__global__ __launch_bounds__(256) void pack_e_kernel(const float* __restrict__ embed,
                                                     uint4* __restrict__ epack) {
  const int t  = blockIdx.x * 256 + threadIdx.x;
  const int l  = t & 63;
  const int ks = (t >> 6) & 7;
  const int ct = t >> 9;
  const int n     = ct * 16 + (l & 15);
  const int kbase = ks * 32 + (l >> 4) * 8;
  unsigned int h[4], lo[4];
  #pragma unroll
  for (int jj = 0; jj < 4; ++jj) {
    const float va = -2.f * embed[(size_t)(kbase + 2 * jj) * NEMB + n];
    const float vb = -2.f * embed[(size_t)(kbase + 2 * jj + 1) * NEMB + n];
    const unsigned short ha = f2bf_rne(va), hb = f2bf_rne(vb);
    const unsigned short la = f2bf_rne(va - bf2f(ha)), lb = f2bf_rne(vb - bf2f(hb));
    h[jj]  = (unsigned int)ha | ((unsigned int)hb << 16);
    lo[jj] = (unsigned int)la | ((unsigned int)lb << 16);
  }
  const size_t base = ((size_t)(ct * 8 + ks) * 2) * 64 + l;
  epack[base]      = make_uint4(h[0], h[1], h[2], h[3]);
  epack[base + 64] = make_uint4(lo[0], lo[1], lo[2], lo[3]);
}

// ---------- MFMA distance + per-row top-2 argmin, XCD-phased chunks ----------
// codes = A (M dim), x-rows = B (N dim). C[m=code][n=row]: each lane's top-2
// covers 4 rows (16 regs). 2 code-tiles per pass + ks-loop NOT unrolled:
// worst-case arch live ~94 regs < the 128 cap at (256,2) -> no spill (rounds
// 6/8 spilled via in-flight load dests of the unrolled c=4 body).
__global__ __launch_bounds__(256, 2) void argmin_mfma_kernel(
    const float* __restrict__ x, const uint4* __restrict__ epack,
    const float* __restrict__ e_sq, float4* __restrict__ partial) {
  __shared__ uint4 xs[4 * 8 * 2 * 64];   // 64 KB: [rt][ks][p][lane] 16B chunks
  __shared__ float4 mbuf[4 * 64];        // 4 KB cross-wave merge

  const int tid  = threadIdx.x;
  const int lane = tid & 63;
  const int w    = tid >> 6;
  const int cc   = blockIdx.x & 7;
  const int row0 = (blockIdx.x >> 3) * 64;
  const int quad = lane >> 4;
  const int lcol = lane & 15;

  // ---- stage + split x into LDS, lane-dense ds_write_b64 order ----
  // g decode: h = g&1 (4-dim half), lp = (g>>1)&63, ks = (g>>7)&7, rt = g>>10
  #pragma unroll 4
  for (int i = 0; i < 16; ++i) {
    const int g   = tid + 256 * i;       // 0..4095
    const int h   = g & 1;
    const int lp  = (g >> 1) & 63;
    const int ks  = (g >> 7) & 7;
    const int rt  = g >> 10;
    const int row = rt * 16 + (lp & 15);
    const int f4  = ks * 8 + (lp >> 4) * 2 + h;
    const float4 v = ((const float4*)(x + (size_t)(row0 + row) * DIM))[f4];
    const unsigned short h0 = f2bf_rne(v.x), h1 = f2bf_rne(v.y),
                         h2 = f2bf_rne(v.z), h3 = f2bf_rne(v.w);
    const unsigned short l0 = f2bf_rne(v.x - bf2f(h0)), l1 = f2bf_rne(v.y - bf2f(h1)),
                         l2 = f2bf_rne(v.z - bf2f(h2)), l3 = f2bf_rne(v.w - bf2f(h3));
    unsigned short* bh = (unsigned short*)&xs[((rt * 8 + ks) * 2 + 0) * 64 + lp] + h * 4;
    unsigned short* bl = (unsigned short*)&xs[((rt * 8 + ks) * 2 + 1) * 64 + lp] + h * 4;
    *(uint2*)bh = make_uint2((unsigned int)h0 | ((unsigned int)h1 << 16),
                             (unsigned int)h2 | ((unsigned int)h3 << 16));
    *(uint2*)bl = make_uint2((unsigned int)l0 | ((unsigned int)l1 << 16),
                             (unsigned int)l2 | ((unsigned int)l3 << 16));
  }
  __syncthreads();

  // per-lane top-2 for 4 rows (one per rt): row = rt*16 + lcol
  float v1[4], v2[4];
  int   j1[4], j2[4];
  #pragma unroll
  for (int r = 0; r < 4; ++r) {
    v1[r] = __builtin_inff(); v2[r] = __builtin_inff();
    j1[r] = 0x7fffffff;       j2[r] = 0x7fffffff;
  }

  // chunk cc covers tiles [cc*64, (cc+1)*64); per cs, wave w takes
  // tiles cc*64 + cs*8 + w*2 + {0,1}  (8 cs passes x 2 tiles = 16 tiles/wave)
  for (int cs = 0; cs < 8; ++cs) {
    const int ct0 = cc * 64 + cs * 8 + w * 2;            // 2 code tiles
    const uint4* pb = epack + (size_t)ct0 * 1024 + lane; // tile stride 1024 uint4

    float4 es[2];
    #pragma unroll
    for (int c = 0; c < 2; ++c)
      es[c] = *(const float4*)(e_sq + (ct0 + c) * 16 + quad * 4);

    f32x4 acc[2][4];   // [c][rt] -> AGPRs
    #pragma unroll
    for (int c = 0; c < 2; ++c)
      #pragma unroll
      for (int rt = 0; rt < 4; ++rt) acc[c][rt] = (f32x4){0.f, 0.f, 0.f, 0.f};

    #pragma unroll 1   // keep only one iteration's loads in flight (reg cap)
    for (int ks = 0; ks < 8; ++ks) {
      short8 eh[2], el[2];
      #pragma unroll
      for (int c = 0; c < 2; ++c) {
        eh[c] = *(const short8*)(pb + c * 1024 + ks * 128);
        el[c] = *(const short8*)(pb + c * 1024 + ks * 128 + 64);
      }
      #pragma unroll
      for (int rt = 0; rt < 4; ++rt) {
        const short8 xh = *(const short8*)&xs[((rt * 8 + ks) * 2 + 0) * 64 + lane];
        const short8 xl = *(const short8*)&xs[((rt * 8 + ks) * 2 + 1) * 64 + lane];
        #pragma unroll
        for (int c = 0; c < 2; ++c) {
          acc[c][rt] = __builtin_amdgcn_mfma_f32_16x16x32_bf16(eh[c], xh, acc[c][rt], 0, 0, 0);
          acc[c][rt] = __builtin_amdgcn_mfma_f32_16x16x32_bf16(el[c], xh, acc[c][rt], 0, 0, 0);
          acc[c][rt] = __builtin_amdgcn_mfma_f32_16x16x32_bf16(eh[c], xl, acc[c][rt], 0, 0, 0);
        }
      }
    }

    // acc = -2*dot ; dist = e_sq[code] + acc ; code = (ct0+c)*16 + quad*4 + r
    #pragma unroll
    for (int c = 0; c < 2; ++c) {
      const int kb = (ct0 + c) * 16 + quad * 4;
      #pragma unroll
      for (int rt = 0; rt < 4; ++rt) {
        top2_bl(v1[rt], j1[rt], v2[rt], j2[rt], es[c].x + acc[c][rt][0], kb + 0);
        top2_bl(v1[rt], j1[rt], v2[rt], j2[rt], es[c].y + acc[c][rt][1], kb + 1);
        top2_bl(v1[rt], j1[rt], v2[rt], j2[rt], es[c].z + acc[c][rt][2], kb + 2);
        top2_bl(v1[rt], j1[rt], v2[rt], j2[rt], es[c].w + acc[c][rt][3], kb + 3);
      }
    }
  }

  // ---- merge across the 4 quads (lanes sharing lcol -> same rows) ----
  #pragma unroll
  for (int rt = 0; rt < 4; ++rt) {
    float a1 = v1[rt], a2 = v2[rt];
    int ia1 = j1[rt], ia2 = j2[rt];
    #pragma unroll
    for (int m = 16; m < 64; m <<= 1) {
      const float b1 = __shfl_xor(a1, m);
      const int  ib1 = __shfl_xor(ia1, m);
      const float b2 = __shfl_xor(a2, m);
      const int  ib2 = __shfl_xor(ia2, m);
      merge_top2(a1, ia1, a2, ia2, b1, ib1, b2, ib2);
    }
    v1[rt] = a1; v2[rt] = a2; j1[rt] = ia1; j2[rt] = ia2;
  }
  if (quad == 0) {
    #pragma unroll
    for (int rt = 0; rt < 4; ++rt)
      mbuf[w * 64 + rt * 16 + lcol] = make_float4(v1[rt], __int_as_float(j1[rt]),
                                                  v2[rt], __int_as_float(j2[rt]));
  }
  __syncthreads();

  if (tid < 64) {
    float4 e0 = mbuf[tid];
    float a1 = e0.x, a2 = e0.z;
    int ia1 = __float_as_int(e0.y), ia2 = __float_as_int(e0.w);
    #pragma unroll
    for (int ww = 1; ww < 4; ++ww) {
      const float4 e = mbuf[ww * 64 + tid];
      merge_top2(a1, ia1, a2, ia2, e.x, __float_as_int(e.y), e.z, __float_as_int(e.w));
    }
    partial[(size_t)cc * NROWS + row0 + tid] =
        make_float4(a1, __int_as_float(ia1), a2, __int_as_float(ia2));
  }
}

// ---------- merge 8 chunk-partials + fp64 refine + gather ----------
template <bool USE_T>
__global__ __launch_bounds__(256) void merge_refine_kernel(
    const float* __restrict__ x, const float* __restrict__ embed,
    const float* __restrict__ embedT, const float4* __restrict__ partial,
    float* __restrict__ out) {
  const int lane = threadIdx.x & 63;
  const int row  = blockIdx.x * 4 + (threadIdx.x >> 6);  // one wave per row

  float a1, a2;
  int ia1, ia2;
  {
    const float4 p0 = partial[row];
    a1 = p0.x; ia1 = __float_as_int(p0.y);
    a2 = p0.z; ia2 = __float_as_int(p0.w);
    #pragma unroll
    for (int cc = 1; cc < NCHUNK; ++cc) {
      const float4 q = partial[(size_t)cc * NROWS + row];
      merge_top2(a1, ia1, a2, ia2, q.x, __float_as_int(q.y), q.z, __float_as_int(q.w));
    }
  }
  const int k1 = ia1;
  const int k2 = ia2;

  const float4 xv = *(const float4*)(x + (size_t)row * DIM + lane * 4);
  float4 e1v, e2v;
  if (USE_T) {
    e1v = *(const float4*)(embedT + (size_t)k1 * DIM + lane * 4);
    e2v = *(const float4*)(embedT + (size_t)k2 * DIM + lane * 4);
  } else {
    const int d = lane * 4;
    e1v.x = embed[(size_t)(d + 0) * NEMB + k1]; e1v.y = embed[(size_t)(d + 1) * NEMB + k1];
    e1v.z = embed[(size_t)(d + 2) * NEMB + k1]; e1v.w = embed[(size_t)(d + 3) * NEMB + k1];
    e2v.x = embed[(size_t)(d + 0) * NEMB + k2]; e2v.y = embed[(size_t)(d + 1) * NEMB + k2];
    e2v.z = embed[(size_t)(d + 2) * NEMB + k2]; e2v.w = embed[(size_t)(d + 3) * NEMB + k2];
  }

  double dot1 = (double)xv.x * e1v.x + (double)xv.y * e1v.y +
                (double)xv.z * e1v.z + (double)xv.w * e1v.w;
  double dot2 = (double)xv.x * e2v.x + (double)xv.y * e2v.y +
                (double)xv.z * e2v.z + (double)xv.w * e2v.w;
  double q1 = (double)e1v.x * e1v.x + (double)e1v.y * e1v.y +
              (double)e1v.z * e1v.z + (double)e1v.w * e1v.w;
  double q2 = (double)e2v.x * e2v.x + (double)e2v.y * e2v.y +
              (double)e2v.z * e2v.z + (double)e2v.w * e2v.w;

  #pragma unroll
  for (int m = 1; m < 64; m <<= 1) {
    dot1 += __shfl_xor(dot1, m);
    dot2 += __shfl_xor(dot2, m);
    q1   += __shfl_xor(q1, m);
    q2   += __shfl_xor(q2, m);
  }

  const double dist1 = q1 - 2.0 * dot1;
  const double dist2 = q2 - 2.0 * dot2;
  const bool pick1 = (dist1 < dist2) || (dist1 == dist2 && k1 <= k2);
  *(float4*)(out + (size_t)row * DIM + lane * 4) = pick1 ? e1v : e2v;
}

// ---------- round-1 fp32 argmin (fallback if ws too small) ----------
__global__ __launch_bounds__(256) void argmin_kernel(
    const float* __restrict__ x, const float* __restrict__ embed,
    const float* __restrict__ e_sq, int* __restrict__ out_i1, int* __restrict__ out_i2) {
  __shared__ float xsh[TM][DIM];
  __shared__ float rv1[4][TM], rv2[4][TM];
  __shared__ int   rj1[4][TM], rj2[4][TM];

  const int tid  = threadIdx.x;
  const int row0 = blockIdx.x * TM;
  {
    const float4* src = (const float4*)(x + (size_t)row0 * DIM);
    float4* dst = (float4*)xsh;
    #pragma unroll
    for (int i = 0; i < (TM * DIM / 4) / 256; ++i)
      dst[tid + 256 * i] = src[tid + 256 * i];
  }
  __syncthreads();

  float v1[TM], v2[TM];
  int   j1[TM], j2[TM];
  #pragma unroll
  for (int r = 0; r < TM; ++r) {
    v1[r] = __builtin_inff(); v2[r] = __builtin_inff();
    j1[r] = 0x7fffffff;       j2[r] = 0x7fffffff;
  }

  for (int c = 0; c < NEMB / (256 * TK); ++c) {
    const int k = c * (256 * TK) + tid * TK;
    float4 acc[TM];
    #pragma unroll
    for (int r = 0; r < TM; ++r) acc[r] = make_float4(0.f, 0.f, 0.f, 0.f);
    const float* eb = embed + k;
    #pragma unroll 2
    for (int d4 = 0; d4 < DIM / 4; ++d4) {
      const int d = d4 * 4;
      const float4 e0 = *(const float4*)(eb + (size_t)(d + 0) * NEMB);
      const float4 e1 = *(const float4*)(eb + (size_t)(d + 1) * NEMB);
      const float4 e2 = *(const float4*)(eb + (size_t)(d + 2) * NEMB);
      const float4 e3 = *(const float4*)(eb + (size_t)(d + 3) * NEMB);
      #pragma unroll
      for (int r = 0; r < TM; ++r) {
        const float4 xv = *(const float4*)&xsh[r][d];
        fma4(acc[r], xv.x, e0); fma4(acc[r], xv.y, e1);
        fma4(acc[r], xv.z, e2); fma4(acc[r], xv.w, e3);
      }
    }
    const float4 es = *(const float4*)(e_sq + k);
    #pragma unroll
    for (int r = 0; r < TM; ++r) {
      top2_bl(v1[r], j1[r], v2[r], j2[r], es.x - 2.f * acc[r].x, k + 0);
      top2_bl(v1[r], j1[r], v2[r], j2[r], es.y - 2.f * acc[r].y, k + 1);
      top2_bl(v1[r], j1[r], v2[r], j2[r], es.z - 2.f * acc[r].z, k + 2);
      top2_bl(v1[r], j1[r], v2[r], j2[r], es.w - 2.f * acc[r].w, k + 3);
    }
  }

  const int lane = tid & 63;
  const int wv   = tid >> 6;
  #pragma unroll
  for (int r = 0; r < TM; ++r) {
    float a1 = v1[r], a2 = v2[r];
    int ia1 = j1[r], ia2 = j2[r];
    #pragma unroll
    for (int m = 1; m < 64; m <<= 1) {
      const float b1 = __shfl_xor(a1, m);
      const int  ib1 = __shfl_xor(ia1, m);
      const float b2 = __shfl_xor(a2, m);
      const int  ib2 = __shfl_xor(ia2, m);
      merge_top2(a1, ia1, a2, ia2, b1, ib1, b2, ib2);
    }
    if (lane == 0) { rv1[wv][r] = a1; rv2[wv][r] = a2; rj1[wv][r] = ia1; rj2[wv][r] = ia2; }
  }
  __syncthreads();

  if (tid < TM) {
    float a1 = rv1[0][tid], a2 = rv2[0][tid];
    int ia1 = rj1[0][tid], ia2 = rj2[0][tid];
    #pragma unroll
    for (int w2 = 1; w2 < 4; ++w2)
      merge_top2(a1, ia1, a2, ia2, rv1[w2][tid], rj1[w2][tid], rv2[w2][tid], rj2[w2][tid]);
    out_i1[row0 + tid] = ia1;
    out_i2[row0 + tid] = ia2;
  }
}

// ---------- old refine (index-pair input, fallback path) ----------
__global__ __launch_bounds__(256) void refine_gather_kernel(
    const float* __restrict__ x, const float* __restrict__ embed,
    const int* __restrict__ in_i1, const int* __restrict__ in_i2,
    float* __restrict__ out) {
  const int lane = threadIdx.x & 63;
  const int row  = blockIdx.x * 4 + (threadIdx.x >> 6);
  const int k1 = in_i1[row];
  const int k2 = in_i2[row];

  const float4 xv = *(const float4*)(x + (size_t)row * DIM + lane * 4);
  float4 e1v, e2v;
  {
    const int d = lane * 4;
    e1v.x = embed[(size_t)(d + 0) * NEMB + k1]; e1v.y = embed[(size_t)(d + 1) * NEMB + k1];
    e1v.z = embed[(size_t)(d + 2) * NEMB + k1]; e1v.w = embed[(size_t)(d + 3) * NEMB + k1];
    e2v.x = embed[(size_t)(d + 0) * NEMB + k2]; e2v.y = embed[(size_t)(d + 1) * NEMB + k2];
    e2v.z = embed[(size_t)(d + 2) * NEMB + k2]; e2v.w = embed[(size_t)(d + 3) * NEMB + k2];
  }

  double dot1 = (double)xv.x * e1v.x + (double)xv.y * e1v.y +
                (double)xv.z * e1v.z + (double)xv.w * e1v.w;
  double dot2 = (double)xv.x * e2v.x + (double)xv.y * e2v.y +
                (double)xv.z * e2v.z + (double)xv.w * e2v.w;
  double q1 = (double)e1v.x * e1v.x + (double)e1v.y * e1v.y +
              (double)e1v.z * e1v.z + (double)e1v.w * e1v.w;
  double q2 = (double)e2v.x * e2v.x + (double)e2v.y * e2v.y +
              (double)e2v.z * e2v.z + (double)e2v.w * e2v.w;

  #pragma unroll
  for (int m = 1; m < 64; m <<= 1) {
    dot1 += __shfl_xor(dot1, m);
    dot2 += __shfl_xor(dot2, m);
    q1   += __shfl_xor(q1, m);
    q2   += __shfl_xor(q2, m);
  }

  const double dist1 = q1 - 2.0 * dot1;
  const double dist2 = q2 - 2.0 * dot2;
  const bool pick1 = (dist1 < dist2) || (dist1 == dist2 && k1 <= k2);
  *(float4*)(out + (size_t)row * DIM + lane * 4) = pick1 ? e1v : e2v;
}

// ---------- launch ----------
extern "C" void kernel_launch(void* const* d_in, const int* in_sizes, int n_in,
                              void* d_out, int out_size, void* d_ws, size_t ws_size,
                              hipStream_t stream) {
  const float* x     = (const float*)d_in[0];
  const float* embed = (const float*)d_in[1];
  float* out = (float*)d_out;

  char* ws = (char*)d_ws;
  const size_t embT_bytes  = (size_t)NEMB * DIM * sizeof(float);          // 8 MB
  const size_t epack_bytes = (size_t)NEMB * DIM * 2 * sizeof(short);      // 8 MB (hi+lo)
  const size_t esq_bytes   = (size_t)NEMB * sizeof(float);                // 32 KB
  const size_t part_bytes  = (size_t)NCHUNK * NROWS * sizeof(float4);     // 4 MB

  const bool tierA = ws_size >= embT_bytes + epack_bytes + esq_bytes + part_bytes;
  const bool tierB = ws_size >= epack_bytes + esq_bytes + part_bytes;

  if (tierA) {
    float*  embedT  = (float*)ws;
    uint4*  epack   = (uint4*)(ws + embT_bytes);
    float*  e_sq    = (float*)(ws + embT_bytes + epack_bytes);
    float4* partial = (float4*)(ws + embT_bytes + epack_bytes + esq_bytes);

    transpose_kernel<<<dim3(NEMB / 64, DIM / 64), 256, 0, stream>>>(embed, embedT);
    esq_kernel<<<NEMB / 256, 256, 0, stream>>>(embed, e_sq);
    pack_e_kernel<<<(NEMB / 16) * 8 * 64 / 256, 256, 0, stream>>>(embed, epack);
    argmin_mfma_kernel<<<(NROWS / 64) * NCHUNK, 256, 0, stream>>>(x, epack, e_sq, partial);
    merge_refine_kernel<true><<<NROWS / 4, 256, 0, stream>>>(x, embed, embedT, partial, out);
  } else if (tierB) {
    uint4*  epack   = (uint4*)ws;
    float*  e_sq    = (float*)(ws + epack_bytes);
    float4* partial = (float4*)(ws + epack_bytes + esq_bytes);

    esq_kernel<<<NEMB / 256, 256, 0, stream>>>(embed, e_sq);
    pack_e_kernel<<<(NEMB / 16) * 8 * 64 / 256, 256, 0, stream>>>(embed, epack);
    argmin_mfma_kernel<<<(NROWS / 64) * NCHUNK, 256, 0, stream>>>(x, epack, e_sq, partial);
    merge_refine_kernel<false><<<NROWS / 4, 256, 0, stream>>>(x, embed, nullptr, partial, out);
  } else {
    float* e_sq = (float*)ws;
    int*   i1   = (int*)(ws + esq_bytes);
    int*   i2   = i1 + NROWS;
    esq_kernel<<<NEMB / 256, 256, 0, stream>>>(embed, e_sq);
    argmin_kernel<<<NROWS / TM, 256, 0, stream>>>(x, embed, e_sq, i1, i2);
    refine_gather_kernel<<<NROWS / 4, 256, 0, stream>>>(x, embed, i1, i2, out);
  }
}